// Round 11
// baseline (1171.024 us; speedup 1.0000x reference)
//
#include <hip/hip_runtime.h>
#include <hip/hip_bf16.h>
#include <cstdint>
#include <cstdio>

// ---------------------------------------------------------------------------
// GATv2 x3 (shared weights layers 2,3) + global max pool, MI355X.
// R29: POOLING FUSED into layer-3 gat_fused epilogue.
//   R28 post-mortem: vectorized pool_max was 110us, WRITE_SIZE 135MB vs
//   5MB output, VALUBusy 3% -> pure atomic-stall. 8 cols/thread made every
//   graph-boundary flush cost 8 atomicMax -> 7.7M device-scope atomics
//   (each an HBM-fabric RMW past the non-coherent per-XCD L2s). Old layout's
//   128-consecutive-u16 row reads were already fully coalesced (256B/wave)
//   -- the currency is ATOMIC COUNT, not load width.
//   R29: the 3rd gat already has each node's final 8 cols in registers and
//   H3 is consumed ONLY by pooling. So layer-3 gat skips the 51MB OUT store
//   and issues 8 no-return atomicMax per node into out (pre-zeroed; ReLU =>
//   >=0 => int-monotone). 1.6M atomics total, batch[n] hoisted to the
//   iteration-top load group. Deletes the pool dispatch AND 51MB write +
//   51MB read. Layers 1-2: pool_out=nullptr (uniform branch).
//   Tripwire: gat-3 > 80us -> atomic contention, revert to separate pool.
// R27 (kept): pk-f32 column math. R26 (kept): merged per-edge phase.
// R22 (kept): DPP red16. R20 (kept): rc/rn double-buffer + 2-deep meta +
//   hoists + guarded uv loads. R19b (kept): sort_scan 4-wide. Grid 1536.
//
// Sorted-CSR (R15): meta[idx]={rp,deg,node} coalesced; recs contiguous at rp.
// Buffers: A = XL, B = XR / H (rotating), both [N][128] bf16.
//   gemm_mfma (K=128): reads H=B rows, writes XL=A + XR=B IN-PLACE (own 64
//     rows; __syncthreads between reads and stores).
// ws ~125 MB (budget 256 MB, checked). No hipMemset* (graph capture).
// ---------------------------------------------------------------------------

typedef __attribute__((ext_vector_type(8))) short bf16x8;           // MFMA frag
typedef __attribute__((ext_vector_type(8))) unsigned short u16x8;   // 16B row chunk
typedef __attribute__((ext_vector_type(4))) float f32x4;
typedef __attribute__((ext_vector_type(2))) float f32x2;            // pk-f32 pair

#define TBT_S 132   // padded LDS table stride (bank spread)

static __device__ __forceinline__ float b2f(unsigned short u) {
    return __uint_as_float(((unsigned)u) << 16);
}
static __device__ __forceinline__ unsigned short f2b(float f) {
    __hip_bfloat16 h = __float2bfloat16(f);
    return *(unsigned short*)&h;
}

// Convert 8 bf16 (4 dwords) -> 4 float2 pairs. Pair k = {elem 2k, elem 2k+1}:
// lo = dword<<16, hi = dword&0xFFFF0000 (1 instr per float, same as scalar).
static __device__ __forceinline__ void b2f2(const u16x8& u, f32x2* out) {
    const unsigned* d = (const unsigned*)&u;
#pragma unroll
    for (int k = 0; k < 4; k++) {
        f32x2 t;
        t.x = __uint_as_float(d[k] << 16);
        t.y = __uint_as_float(d[k] & 0xFFFF0000u);
        out[k] = t;
    }
}

// Sum across each 16-lane row via DPP (no LDS/DS-pipe ops, no extra VGPR).
// Stages: quad_perm[1,0,3,2] (xor1), quad_perm[2,3,0,1] (xor2) -> quad sums;
// row_ror:4 + row_ror:8 -> sum of the 4 quad-sums. All 16 lanes get the total.
static __device__ __forceinline__ float red16(float p) {
    float t;
    t = __int_as_float(__builtin_amdgcn_update_dpp(
            0, __float_as_int(p), 0xB1, 0xF, 0xF, true));   // quad_perm xor1
    p += t;
    t = __int_as_float(__builtin_amdgcn_update_dpp(
            0, __float_as_int(p), 0x4E, 0xF, 0xF, true));   // quad_perm xor2
    p += t;
    t = __int_as_float(__builtin_amdgcn_update_dpp(
            0, __float_as_int(p), 0x124, 0xF, 0xF, true));  // row_ror:4
    p += t;
    t = __int_as_float(__builtin_amdgcn_update_dpp(
            0, __float_as_int(p), 0x128, 0xF, 0xF, true));  // row_ror:8
    p += t;
    return p;
}

// ---------------- consolidated init: zeros + weight packs + feature build ---

__global__ __launch_bounds__(256) void prep_init(
    int* __restrict__ degcnt, int n_degcnt,
    int* __restrict__ outz, int n_out,
    const float* __restrict__ Wl2, const float* __restrict__ Wr2,
    __hip_bfloat16* __restrict__ Wp,
    const float* __restrict__ Wl1, const float* __restrict__ Wr1,
    __hip_bfloat16* __restrict__ Wp1,
    const int* __restrict__ atom_num, const int* __restrict__ atom_arom,
    const float* __restrict__ x_cont, const float* __restrict__ atom_emb,
    const float* __restrict__ bool_emb, __hip_bfloat16* __restrict__ Xf, int N,
    int e_z1, int e_z2, int e_pw, int e_pw1)   // exclusive block-range ends
{
    int b = blockIdx.x;
    if (b < e_z1) {                       // zero degcnt
        int i = b * 256 + threadIdx.x;
        if (i < n_degcnt) degcnt[i] = 0;
    } else if (b < e_z2) {                // zero out
        int i = (b - e_z1) * 256 + threadIdx.x;
        if (i < n_out) outz[i] = 0;
    } else if (b < e_pw) {                // pack W2 (32768 frags)
        int idx = (b - e_z2) * 256 + threadIdx.x;
        int j    = idx & 7;
        int lane = (idx >> 3) & 63;
        int ks   = (idx >> 9) & 3;
        int nt   = idx >> 11;
        int k = ks * 32 + ((lane >> 4) << 3) + j;
        int n = nt * 16 + (lane & 15);
        float v = (n < 128) ? Wl2[k * 128 + n] : Wr2[k * 128 + (n - 128)];
        Wp[idx] = __float2bfloat16(v);
    } else if (b < e_pw1) {               // pack W1 (8192 frags, K pad 26->32)
        int idx = (b - e_pw) * 256 + threadIdx.x;
        int j    = idx & 7;
        int lane = (idx >> 3) & 63;
        int ntc  = idx >> 9;
        int k = ((lane >> 4) << 3) + j;
        int n = ntc * 16 + (lane & 15);
        float v = 0.f;
        if (k < 26) v = (n < 128) ? Wl1[k * 128 + n] : Wr1[k * 128 + (n - 128)];
        Wp1[idx] = __float2bfloat16(v);
    } else {                              // build Xf[N][32]
        int n = (b - e_pw1) * 256 + threadIdx.x;
        if (n >= N) return;
        int an = atom_num[n], am = atom_arom[n];
        unsigned short v[32];
#pragma unroll
        for (int k = 0; k < 16; k++) v[k] = f2b(atom_emb[an * 16 + k]);
#pragma unroll
        for (int k = 0; k < 8; k++)  v[16 + k] = f2b(x_cont[(size_t)n * 8 + k]);
        v[24] = f2b(bool_emb[am * 2]);
        v[25] = f2b(bool_emb[am * 2 + 1]);
#pragma unroll
        for (int k = 26; k < 32; k++) v[k] = 0;
        unsigned short* dst = (unsigned short*)Xf + (size_t)n * 32;
#pragma unroll
        for (int q = 0; q < 4; q++)
            *(u16x8*)(dst + q * 8) = *(const u16x8*)&v[q * 8];
    }
}

// ---------------- prep kernels ----------------

__global__ __launch_bounds__(256) void count_deg(
    const int* __restrict__ dst, int* __restrict__ deg, int E)
{
    int e = blockIdx.x * 256 + threadIdx.x;
    if (e < E) atomicAdd(&deg[dst[e]], 1);
}

// ---- degree counting sort (contention-free) + sorted-CSR layout ----
#define SORT_BLK 1024

__global__ __launch_bounds__(256) void sort_hist(
    const int* __restrict__ deg, int* __restrict__ block_hist, int N)
{
    __shared__ int h[512];
    for (int i = threadIdx.x; i < 512; i += 256) h[i] = 0;
    __syncthreads();
    int base = blockIdx.x * SORT_BLK;
#pragma unroll
    for (int k = 0; k < 4; k++) {
        int n = base + k * 256 + threadIdx.x;
        if (n < N) {
            int d = deg[n]; if (d > 511) d = 511;
            atomicAdd(&h[d], 1);              // LDS atomic, block-local
        }
    }
    __syncthreads();
    for (int i = threadIdx.x; i < 512; i += 256)
        block_hist[blockIdx.x * 512 + i] = h[i];
}

// One block, 512 threads: thread t owns bin t. Column-scan across sort blocks
// (block_hist -> per-block exclusive offsets), then two bin scans:
// bin_base[d] (node positions) and edge_base[d] (edge positions, weight d).
// R19b: column scan batched 4-wide -> 4 loads in flight instead of a serial
// load->add->load chain (single-block kernel, latency-bound).
__global__ __launch_bounds__(512) void sort_scan(
    int* __restrict__ block_hist, int* __restrict__ bin_base,
    int* __restrict__ edge_base, int nsb)
{
    __shared__ int s[512];
    int t = threadIdx.x;
    int acc = 0;
    int b = 0;
    for (; b + 4 <= nsb; b += 4) {
        int v0 = block_hist[(b + 0) * 512 + t];
        int v1 = block_hist[(b + 1) * 512 + t];
        int v2 = block_hist[(b + 2) * 512 + t];
        int v3 = block_hist[(b + 3) * 512 + t];
        block_hist[(b + 0) * 512 + t] = acc; acc += v0;
        block_hist[(b + 1) * 512 + t] = acc; acc += v1;
        block_hist[(b + 2) * 512 + t] = acc; acc += v2;
        block_hist[(b + 3) * 512 + t] = acc; acc += v3;
    }
    for (; b < nsb; b++) {
        int v = block_hist[b * 512 + t];
        block_hist[b * 512 + t] = acc;
        acc += v;
    }
    // scan 1: node counts -> bin_base
    s[t] = acc;
    __syncthreads();
    for (int off = 1; off < 512; off <<= 1) {
        int x = (t >= off) ? s[t - off] : 0;
        __syncthreads();
        s[t] += x;
        __syncthreads();
    }
    bin_base[t] = s[t] - acc;
    __syncthreads();
    // scan 2: edge counts (count*d) -> edge_base
    int ec = acc * t;
    s[t] = ec;
    __syncthreads();
    for (int off = 1; off < 512; off <<= 1) {
        int x = (t >= off) ? s[t - off] : 0;
        __syncthreads();
        s[t] += x;
        __syncthreads();
    }
    edge_base[t] = s[t] - ec;
}

// Scatter: meta[pos] = {rp_sorted, deg, node, 0}; nrp[node] = rp_sorted.
__global__ __launch_bounds__(256) void sort_scatter(
    const int* __restrict__ deg, const int* __restrict__ block_hist,
    const int* __restrict__ bin_base, const int* __restrict__ edge_base,
    int4* __restrict__ meta, int* __restrict__ nrp, int N)
{
    __shared__ int h[512];
    for (int i = threadIdx.x; i < 512; i += 256) h[i] = 0;
    __syncthreads();
    int bs = blockIdx.x;
    int base = bs * SORT_BLK;
#pragma unroll
    for (int k = 0; k < 4; k++) {
        int n = base + k * 256 + threadIdx.x;
        if (n < N) {
            int d = deg[n]; if (d > 511) d = 511;
            int r = atomicAdd(&h[d], 1);      // LDS atomic rank
            int posInBin = block_hist[bs * 512 + d] + r;
            int pos = bin_base[d] + posInBin;
            int rp = edge_base[d] + posInBin * d;
            int4 m; m.x = rp; m.y = d; m.z = n; m.w = 0;
            meta[pos] = m;
            nrp[n] = rp;
        }
    }
}

// Fill sorted CSR with PACKED per-slot records {src, codes, ec_bits, 0}.
__global__ __launch_bounds__(256) void csr_fill(
    const int* __restrict__ src, const int* __restrict__ dst,
    const int* __restrict__ bond_type, const float* __restrict__ edge_cont,
    const int* __restrict__ bond_conj, const int* __restrict__ bond_arom,
    const int* __restrict__ nrp, int* __restrict__ cnt,
    int4* __restrict__ csr_rec, int E)
{
    int e = blockIdx.x * 256 + threadIdx.x;
    if (e >= E) return;
    int d = dst[e];
    int pos = nrp[d] + atomicAdd(&cnt[d], 1);
    int codes = (bond_type[e] & 0xFF) | ((bond_conj[e] & 1) << 8) | ((bond_arom[e] & 1) << 16);
    int4 rec;
    rec.x = src[e];
    rec.y = codes;
    rec.z = __float_as_int(edge_cont[e]);
    rec.w = 0;
    csr_rec[pos] = rec;
}

// ---------------- per-layer kernels ----------------

// Layer-1 GEMM via MFMA, K=32 (single step): Xfeat[N][32] @ Wp1 -> XL|XR.
__global__ __launch_bounds__(256) void gemm_mfma1(
    const __hip_bfloat16* __restrict__ Xf,   // [N][32]
    const __hip_bfloat16* __restrict__ Wp,   // packed frags, 8192 bf16
    const float* __restrict__ bl, const float* __restrict__ br,
    __hip_bfloat16* __restrict__ XL, __hip_bfloat16* __restrict__ XR, int N)
{
    __shared__ unsigned short sT[64 * 256];   // 32 KB output tile
    int lane = threadIdx.x & 63;
    int wave = threadIdx.x >> 6;
    int row0 = blockIdx.x * 64;
    int m_lane = lane & 15;
    int quad = lane >> 4;
    const unsigned short* Xu = (const unsigned short*)Xf;
    const unsigned short* Wu = (const unsigned short*)Wp;

    f32x4 acc[4][4];
#pragma unroll
    for (int mt = 0; mt < 4; mt++)
#pragma unroll
        for (int nt = 0; nt < 4; nt++) acc[mt][nt] = (f32x4){0.f, 0.f, 0.f, 0.f};

    bf16x8 a[4], b[4];
#pragma unroll
    for (int mt = 0; mt < 4; mt++)
        a[mt] = *(const bf16x8*)(Xu + (size_t)(row0 + mt * 16 + m_lane) * 32 + quad * 8);
#pragma unroll
    for (int nt = 0; nt < 4; nt++)
        b[nt] = *(const bf16x8*)(Wu + ((wave * 4 + nt) * 64 + lane) * 8);
#pragma unroll
    for (int mt = 0; mt < 4; mt++)
#pragma unroll
        for (int nt = 0; nt < 4; nt++)
            acc[mt][nt] = __builtin_amdgcn_mfma_f32_16x16x32_bf16(
                a[mt], b[nt], acc[mt][nt], 0, 0, 0);

#pragma unroll
    for (int nt = 0; nt < 4; nt++) {
        int col = wave * 64 + nt * 16 + m_lane;
        float bv = (col < 128) ? bl[col] : br[col - 128];
#pragma unroll
        for (int mt = 0; mt < 4; mt++) {
            int rbase = mt * 16 + quad * 4;
#pragma unroll
            for (int reg = 0; reg < 4; reg++)
                sT[(rbase + reg) * 256 + col] = f2b(acc[mt][nt][reg] + bv);
        }
    }

    __syncthreads();

    unsigned short* XLu = (unsigned short*)XL;
    unsigned short* XRu = (unsigned short*)XR;
    int t = threadIdx.x;
#pragma unroll
    for (int q = 0; q < 4; q++) {
        int s = t * 32 + q * 8;
        int r = s >> 7, c = s & 127;
        *(u16x8*)(XLu + (size_t)(row0 + r) * 128 + c) = *(const u16x8*)&sT[r * 256 + c];
        *(u16x8*)(XRu + (size_t)(row0 + r) * 128 + c) = *(const u16x8*)&sT[r * 256 + 128 + c];
    }
}

// Layers 2/3 GEMM via MFMA (K=128) with LDS-staged coalesced epilogue.
__global__ __launch_bounds__(256) void gemm_mfma(
    const __hip_bfloat16* H,               // [N][128]  (aliases XR)
    const __hip_bfloat16* __restrict__ Wp, // packed frags, 32768 bf16
    const float* __restrict__ bl, const float* __restrict__ br,
    __hip_bfloat16* __restrict__ XL, __hip_bfloat16* XR, int N)
{
    __shared__ unsigned short sT[64 * 256];   // 32 KB output tile
    int lane = threadIdx.x & 63;
    int wave = threadIdx.x >> 6;
    int row0 = blockIdx.x * 64;
    int m_lane = lane & 15;
    int quad = lane >> 4;
    const unsigned short* Hu = (const unsigned short*)H;
    const unsigned short* Wu = (const unsigned short*)Wp;

    f32x4 acc[4][4];
#pragma unroll
    for (int mt = 0; mt < 4; mt++)
#pragma unroll
        for (int nt = 0; nt < 4; nt++) acc[mt][nt] = (f32x4){0.f, 0.f, 0.f, 0.f};

#pragma unroll
    for (int ks = 0; ks < 4; ks++) {
        int koff = ks * 32 + quad * 8;
        bf16x8 a[4], b[4];
#pragma unroll
        for (int mt = 0; mt < 4; mt++)
            a[mt] = *(const bf16x8*)(Hu + (size_t)(row0 + mt * 16 + m_lane) * 128 + koff);
#pragma unroll
        for (int nt = 0; nt < 4; nt++)
            b[nt] = *(const bf16x8*)(Wu + ((((wave * 4 + nt) * 4) + ks) * 64 + lane) * 8);
#pragma unroll
        for (int mt = 0; mt < 4; mt++)
#pragma unroll
            for (int nt = 0; nt < 4; nt++)
                acc[mt][nt] = __builtin_amdgcn_mfma_f32_16x16x32_bf16(
                    a[mt], b[nt], acc[mt][nt], 0, 0, 0);
    }

#pragma unroll
    for (int nt = 0; nt < 4; nt++) {
        int col = wave * 64 + nt * 16 + m_lane;
        float bv = (col < 128) ? bl[col] : br[col - 128];
#pragma unroll
        for (int mt = 0; mt < 4; mt++) {
            int rbase = mt * 16 + quad * 4;
#pragma unroll
            for (int reg = 0; reg < 4; reg++)
                sT[(rbase + reg) * 256 + col] = f2b(acc[mt][nt][reg] + bv);
        }
    }

    __syncthreads();   // also drains all H loads before any XR store

    unsigned short* XLu = (unsigned short*)XL;
    unsigned short* XRu = (unsigned short*)XR;
    int t = threadIdx.x;
#pragma unroll
    for (int q = 0; q < 4; q++) {
        int s = t * 32 + q * 8;            // short index within 64x128 tile
        int r = s >> 7, c = s & 127;
        *(u16x8*)(XLu + (size_t)(row0 + r) * 128 + c) = *(const u16x8*)&sT[r * 256 + c];
        *(u16x8*)(XRu + (size_t)(row0 + r) * 128 + c) = *(const u16x8*)&sT[r * 256 + 128 + c];
    }
}

// FUSED logits + softmax + aggregate. 16-lane sub-waves, 4 nodes/wave.
// R27 pk-f32 column math; R29: optional fused global-max-pool epilogue.
// pool_out == nullptr: store OUT row (layers 1,2).
// pool_out != nullptr: 8 no-return atomicMax into pool_out[batch[n]*128+..]
//   and SKIP the OUT store (layer 3; H3 is only consumed by pooling).
__global__ __launch_bounds__(256) void gat_fused(
    const int4* __restrict__ meta, const int4* __restrict__ csr_rec,
    const float* __restrict__ bond_emb, const float* __restrict__ bool_emb,
    const __hip_bfloat16* __restrict__ XL, const __hip_bfloat16* XR,
    const float* __restrict__ We,        // [13][128]
    const float* __restrict__ att,       // [128]
    const float* __restrict__ bias,      // [128]
    __hip_bfloat16* OUT,
    const int* __restrict__ batch,       // node -> graph (used when pooling)
    float* pool_out,                     // nullptr => no fused pool
    int N)
{
    __shared__ float sTbt[22 * TBT_S];   // bond_emb[bt] @ We[0:8], padded stride
    __shared__ float sTca[4 * TBT_S];    // bool-pair terms
    __shared__ float sW8[128];           // We[8,:]

    for (int i = threadIdx.x; i < 22 * 128; i += 256) {
        int bt = i >> 7, c = i & 127;
        float s = 0.f;
#pragma unroll
        for (int k = 0; k < 8; k++) s = fmaf(bond_emb[bt * 8 + k], We[k * 128 + c], s);
        sTbt[bt * TBT_S + c] = s;
    }
    for (int i = threadIdx.x; i < 4 * 128; i += 256) {
        int idx = i >> 7, c = i & 127;
        int cj = idx >> 1, ar = idx & 1;
        float s = bool_emb[cj * 2]     * We[9 * 128 + c]
                + bool_emb[cj * 2 + 1] * We[10 * 128 + c]
                + bool_emb[ar * 2]     * We[11 * 128 + c]
                + bool_emb[ar * 2 + 1] * We[12 * 128 + c];
        sTca[idx * TBT_S + c] = s;
    }
    if (threadIdx.x < 128) sW8[threadIdx.x] = We[8 * 128 + threadIdx.x];
    __syncthreads();

    int lane = threadIdx.x & 63;
    int wave = threadIdx.x >> 6;
    int sl   = lane & 15;
    int sw   = lane >> 4;
    int cbase = sl * 8;

    f32x2 a82[4], bs82[4], w882[4];
    {
        float4 t0 = *(const float4*)&att[cbase],  t1 = *(const float4*)&att[cbase + 4];
        float4 u0 = *(const float4*)&bias[cbase], u1 = *(const float4*)&bias[cbase + 4];
        float4 v0 = *(const float4*)&sW8[cbase],  v1 = *(const float4*)&sW8[cbase + 4];
        a82[0] = (f32x2){t0.x, t0.y};  a82[1] = (f32x2){t0.z, t0.w};
        a82[2] = (f32x2){t1.x, t1.y};  a82[3] = (f32x2){t1.z, t1.w};
        bs82[0] = (f32x2){u0.x, u0.y}; bs82[1] = (f32x2){u0.z, u0.w};
        bs82[2] = (f32x2){u1.x, u1.y}; bs82[3] = (f32x2){u1.z, u1.w};
        w882[0] = (f32x2){v0.x, v0.y}; w882[1] = (f32x2){v0.z, v0.w};
        w882[2] = (f32x2){v1.x, v1.y}; w882[3] = (f32x2){v1.z, v1.w};
    }

    const unsigned short* XLu = (const unsigned short*)XL;
    const unsigned short* XRu = (const unsigned short*)XR;
    unsigned short* OUTu = (unsigned short*)OUT;
    int* pouti = (int*)pool_out;

    int group = (blockIdx.x * 4 + wave) * 4 + sw;   // global sub-wave id
    int stride = gridDim.x * 16;

    if (group >= N) return;

    // ---- pipeline prologue ----
    int4 mt  = meta[group];                               // node i
    int ni   = group + stride;
    int4 mtn = meta[(ni < N) ? ni : (N - 1)];             // node i+1
    int4 rc[4];                                           // recs for i, chunk 0
    {
        int rp0 = mt.x, dg0 = mt.y;
#pragma unroll
        for (int jj = 0; jj < 4; jj++)
            rc[jj] = csr_rec[rp0 + (jj < dg0 ? jj : 0)];  // clamped: always valid
    }

    for (int idx = group; idx < N; idx += stride) {
        const int rp = mt.x, dg = mt.y, n = mt.z;

        // independent long-latency issues at iteration top:
        u16x8 uxr = *(const u16x8*)(XRu + (size_t)n * 128 + cbase);     // own XR
        u16x8 un  = *(const u16x8*)(XLu + (size_t)n * 128 + cbase);     // self XL
        int i2 = idx + 2 * stride;
        int4 mt2 = meta[(i2 < N) ? i2 : (N - 1)];                       // node i+2
        int gb = pouti ? batch[n] : 0;                                  // graph id

        f32x2 xr2[4];
        b2f2(uxr, xr2);

        float runs = 0.f;
        f32x2 acc2[4], ets2[4];
#pragma unroll
        for (int i = 0; i < 4; i++) {
            acc2[i] = (f32x2){0.f, 0.f};
            ets2[i] = (f32x2){0.f, 0.f};
        }

        int j = 0;
        do {   // runs once even for dg==0 (cnt=0) so rc advances to next node
            int cnt = dg - j;
            cnt = cnt < 0 ? 0 : (cnt > 4 ? 4 : cnt);

            // uv gathers issue NOW from prefetched records (one memory round);
            // GUARDED (R24: unconditional clamped loads lengthen vmcnt drain)
            u16x8 uv[4];
#pragma unroll
            for (int jj = 0; jj < 4; jj++)
                if (jj < cnt)
                    uv[jj] = *(const u16x8*)(XLu + (size_t)rc[jj].x * 128 + cbase);

            // prefetch next chunk: in-node j+4, else next node's first chunk
            // (mtn is register-resident thanks to the 2-deep meta pipeline)
            int innode = (j + 4 < dg);
            int nb = innode ? (rp + j + 4) : mtn.x;
            int nd = innode ? (dg - j - 4) : mtn.y;
            int4 rn[4];
#pragma unroll
            for (int jj = 0; jj < 4; jj++)
                rn[jj] = csr_rec[nb + (jj < nd ? jj : 0)];   // clamped: valid

            // merged per-edge phase (R26), packed-f32 column math (R27).
#pragma unroll
            for (int jj = 0; jj < 4; jj++) {
                if (jj >= cnt) continue;
                int bt = rc[jj].y & 0xFF;
                int ca = (((rc[jj].y >> 8) & 1) << 1) | ((rc[jj].y >> 16) & 1);
                float ec = __int_as_float(rc[jj].z);
                const f32x2* tb = (const f32x2*)&sTbt[bt * TBT_S + cbase];
                const f32x2* tc = (const f32x2*)&sTca[ca * TBT_S + cbase];
                f32x2 uvf[4];
                b2f2(uv[jj], uvf);
                f32x2 ec2 = (f32x2){ec, ec};
                f32x2 ps = (f32x2){0.f, 0.f};
#pragma unroll
                for (int i = 0; i < 4; i++) {
                    f32x2 et = __builtin_elementwise_fma(ec2, w882[i], tb[i] + tc[i]);
                    ets2[i] += et;
                    f32x2 v = xr2[i] + uvf[i] + et;
                    f32x2 m = __builtin_elementwise_max(v, 0.2f * v);  // leaky 0.2
                    ps = __builtin_elementwise_fma(m, a82[i], ps);
                }
                float p = red16(ps.x + ps.y);  // DPP reduce, no DS ops
                float wgt = __expf(p);
                runs += wgt;
                f32x2 w2 = (f32x2){wgt, wgt};
#pragma unroll
                for (int i = 0; i < 4; i++)
                    acc2[i] = __builtin_elementwise_fma(w2, uvf[i], acc2[i]);
            }
#pragma unroll
            for (int jj = 0; jj < 4; jj++) rc[jj] = rn[jj];
            j += 4;
        } while (j < dg);

        {   // self loop (un in flight since iteration top)
            float invd = 1.f / (float)(dg > 0 ? dg : 1);
            f32x2 iv2 = (f32x2){invd, invd};
            f32x2 unf[4];
            b2f2(un, unf);
            f32x2 ps = (f32x2){0.f, 0.f};
#pragma unroll
            for (int i = 0; i < 4; i++) {
                f32x2 v = __builtin_elementwise_fma(ets2[i], iv2, xr2[i] + unf[i]);
                f32x2 m = __builtin_elementwise_max(v, 0.2f * v);
                ps = __builtin_elementwise_fma(m, a82[i], ps);
            }
            float p = red16(ps.x + ps.y);
            float wgt = __expf(p);
            runs += wgt;
            f32x2 w2 = (f32x2){wgt, wgt};
#pragma unroll
            for (int i = 0; i < 4; i++)
                acc2[i] = __builtin_elementwise_fma(w2, unf[i], acc2[i]);
        }

        float inv = 1.f / runs;
        f32x2 iv2 = (f32x2){inv, inv};
        if (pouti) {
            // fused pool: 8 no-return atomicMax (values >= 0; out pre-zeroed)
            int* og = pouti + (size_t)gb * 128 + cbase;
#pragma unroll
            for (int i = 0; i < 4; i++) {
                f32x2 r = __builtin_elementwise_fma(acc2[i], iv2, bs82[i]);
                f32x2 z = (f32x2){0.f, 0.f};
                r = __builtin_elementwise_max(r, z);   // ReLU
                atomicMax(og + 2 * i,     __float_as_int(r.x));
                atomicMax(og + 2 * i + 1, __float_as_int(r.y));
            }
        } else {
            u16x8 o;
#pragma unroll
            for (int i = 0; i < 4; i++) {
                f32x2 r = __builtin_elementwise_fma(acc2[i], iv2, bs82[i]);
                f32x2 z = (f32x2){0.f, 0.f};
                r = __builtin_elementwise_max(r, z);   // ReLU
                o[2 * i]     = f2b(r.x);
                o[2 * i + 1] = f2b(r.y);
            }
            *(u16x8*)(OUTu + (size_t)n * 128 + cbase) = o;
        }

        // rotate meta pipeline
        mt = mtn; mtn = mt2;
    }
}

// ---------------------------------------------------------------------------

static inline size_t align_up(size_t x, size_t a) { return (x + a - 1) & ~(a - 1); }
static inline int cdiv(int a, int b) { return (a + b - 1) / b; }

extern "C" void kernel_launch(void* const* d_in, const int* in_sizes, int n_in,
                              void* d_out, int out_size, void* d_ws, size_t ws_size,
                              hipStream_t stream)
{
    const int N = in_sizes[0];          // 200000 (multiple of 64)
    const int E = in_sizes[3];          // 800000

    const int*   atom_num  = (const int*)d_in[0];
    const int*   atom_arom = (const int*)d_in[1];
    const float* x_cont    = (const float*)d_in[2];
    const int*   bond_type = (const int*)d_in[3];
    const float* edge_cont = (const float*)d_in[4];
    const int*   bond_conj = (const int*)d_in[5];
    const int*   bond_arom = (const int*)d_in[6];
    const int*   e_src     = (const int*)d_in[7];
    const int*   e_dst     = e_src + E;
    const int*   batch     = (const int*)d_in[8];
    const float* atom_emb  = (const float*)d_in[9];
    const float* bond_emb  = (const float*)d_in[10];
    const float* bool_emb  = (const float*)d_in[11];
    const float* Wl1 = (const float*)d_in[12]; const float* bl1 = (const float*)d_in[13];
    const float* Wr1 = (const float*)d_in[14]; const float* br1 = (const float*)d_in[15];
    const float* We1 = (const float*)d_in[16]; const float* att1 = (const float*)d_in[17];
    const float* bias1 = (const float*)d_in[18];
    const float* Wl2 = (const float*)d_in[19]; const float* bl2 = (const float*)d_in[20];
    const float* Wr2 = (const float*)d_in[21]; const float* br2 = (const float*)d_in[22];
    const float* We2 = (const float*)d_in[23]; const float* att2 = (const float*)d_in[24];
    const float* bias2 = (const float*)d_in[25];
    float* out = (float*)d_out;

    const int nsb = cdiv(N, SORT_BLK);  // sort blocks (196)

    // ---- workspace layout (~125 MB; ws_size is 256 MB) ----
    char* w = (char*)d_ws;
    size_t off = 0;
    auto alloc = [&](size_t bytes) {
        void* p = w + off;
        off = align_up(off + bytes, 256);
        return p;
    };
    __hip_bfloat16* A  = (__hip_bfloat16*)alloc((size_t)N * 128 * 2);   // XL
    __hip_bfloat16* B  = (__hip_bfloat16*)alloc((size_t)N * 128 * 2);   // XR / H
    __hip_bfloat16* Xf = (__hip_bfloat16*)alloc((size_t)N * 32 * 2);    // layer-1 feats
    __hip_bfloat16* Wp = (__hip_bfloat16*)alloc((size_t)32768 * 2);     // packed W2
    __hip_bfloat16* Wp1= (__hip_bfloat16*)alloc((size_t)8192 * 2);      // packed W1
    int*   degcnt  = (int*)alloc((size_t)2 * N * 4);
    int*   deg     = degcnt;
    int*   cnt     = degcnt + N;
    int4*  csr_rec = (int4*)alloc((size_t)E * 16);
    int4*  meta    = (int4*)alloc((size_t)N * 16);
    int*   nrp     = (int*)alloc((size_t)N * 4);
    int*   block_hist = (int*)alloc((size_t)nsb * 512 * 4);
    int*   bin_base   = (int*)alloc(512 * 4);
    int*   edge_base  = (int*)alloc(512 * 4);
    size_t required = off;

    fprintf(stderr, "[GNN] ws_size=%zu required=%zu%s\n", ws_size, required,
            ws_size < required ? "  INSUFFICIENT - skipping" : "");
    if (ws_size < required) return;

    // ---- consolidated init (zeros + packs + feature build), one dispatch ----
    int bz1 = cdiv(2 * N, 256);
    int bz2 = cdiv(out_size, 256);
    int bpw = 32768 / 256;
    int bpw1 = 8192 / 256;
    int bbx = cdiv(N, 256);
    int e_z1 = bz1, e_z2 = e_z1 + bz2, e_pw = e_z2 + bpw, e_pw1 = e_pw + bpw1;
    prep_init<<<e_pw1 + bbx, 256, 0, stream>>>(
        degcnt, 2 * N, (int*)out, out_size,
        Wl2, Wr2, Wp, Wl1, Wr1, Wp1,
        atom_num, atom_arom, x_cont, atom_emb, bool_emb, Xf, N,
        e_z1, e_z2, e_pw, e_pw1);

    // ---- prep: degree sort + sorted CSR (5 dispatches after prep_init) ----
    count_deg<<<cdiv(E, 256), 256, 0, stream>>>(e_dst, deg, E);
    sort_hist<<<nsb, 256, 0, stream>>>(deg, block_hist, N);
    sort_scan<<<1, 512, 0, stream>>>(block_hist, bin_base, edge_base, nsb);
    sort_scatter<<<nsb, 256, 0, stream>>>(deg, block_hist, bin_base, edge_base,
                                          meta, nrp, N);
    csr_fill<<<cdiv(E, 256), 256, 0, stream>>>(e_src, e_dst, bond_type, edge_cont,
                                               bond_conj, bond_arom, nrp, cnt,
                                               csr_rec, E);

    // R26/R27: proven geometry.
    const int fused_blocks = 1536;

    // ---- layer 1: Xf -> A(XL), B(XR) via MFMA; fused -> B(H1) ----
    gemm_mfma1<<<N / 64, 256, 0, stream>>>(Xf, Wp1, bl1, br1, A, B, N);
    gat_fused<<<fused_blocks, 256, 0, stream>>>(
        meta, csr_rec, bond_emb, bool_emb, A, B, We1, att1, bias1, B,
        nullptr, nullptr, N);

    // ---- layer 2: B -> A, B(in-place); fused -> B(H2) ----
    gemm_mfma<<<N / 64, 256, 0, stream>>>(B, Wp, bl2, br2, A, B, N);
    gat_fused<<<fused_blocks, 256, 0, stream>>>(
        meta, csr_rec, bond_emb, bool_emb, A, B, We2, att2, bias2, B,
        nullptr, nullptr, N);

    // ---- layer 3 with FUSED global max pool into d_out (R29) ----
    gemm_mfma<<<N / 64, 256, 0, stream>>>(B, Wp, bl2, br2, A, B, N);
    gat_fused<<<fused_blocks, 256, 0, stream>>>(
        meta, csr_rec, bond_emb, bool_emb, A, B, We2, att2, bias2, B,
        batch, out, N);
}

// Round 12
// 1146.600 us; speedup vs baseline: 1.0213x; 1.0213x over previous
//
#include <hip/hip_runtime.h>
#include <hip/hip_bf16.h>
#include <cstdint>
#include <cstdio>

// ---------------------------------------------------------------------------
// GATv2 x3 (shared weights layers 2,3) + global max pool, MI355X.
// R30: fused pool done RIGHT — template<bool POOL> gat_fused.
//   R29 post-mortem: runtime `if (pool_out)` dual epilogue poisoned ALL
//   THREE gat dispatches: WRITE_SIZE 50->800MB even with pool_out==nullptr,
//   VALUBusy 54->5.8% => per-iteration SCRATCH spill (R19 signature),
//   caused by keeping both epilogue paths' state live in the hot loop.
//   Atomics were innocent (layer-3 would be ~27MB; layers 1-2 had none).
//   Fix: compile-time variant. POOL=false == R27 codegen exactly (proven
//   68.3us); POOL=true (layer 3 only) skips the 51MB OUT store and issues
//   8 no-return atomicMax per node into pre-zeroed out (ReLU => >=0 =>
//   int-monotone). ~1.6M atomics total. Deletes the pool dispatch.
//   Tripwire: layer-3 > 90us or WRITE >> 50MB -> unfuse next round.
// R27 (kept): pk-f32 column math. R26 (kept): merged per-edge phase.
// R22 (kept): DPP red16. R20 (kept): rc/rn double-buffer + 2-deep meta +
//   hoists + guarded uv loads. R19b (kept): sort_scan 4-wide. Grid 1536.
//
// Sorted-CSR (R15): meta[idx]={rp,deg,node} coalesced; recs contiguous at rp.
// Buffers: A = XL, B = XR / H (rotating), both [N][128] bf16.
//   gemm_mfma (K=128): reads H=B rows, writes XL=A + XR=B IN-PLACE (own 64
//     rows; __syncthreads between reads and stores).
// ws ~125 MB (budget 256 MB, checked). No hipMemset* (graph capture).
// ---------------------------------------------------------------------------

typedef __attribute__((ext_vector_type(8))) short bf16x8;           // MFMA frag
typedef __attribute__((ext_vector_type(8))) unsigned short u16x8;   // 16B row chunk
typedef __attribute__((ext_vector_type(4))) float f32x4;
typedef __attribute__((ext_vector_type(2))) float f32x2;            // pk-f32 pair

#define TBT_S 132   // padded LDS table stride (bank spread)

static __device__ __forceinline__ float b2f(unsigned short u) {
    return __uint_as_float(((unsigned)u) << 16);
}
static __device__ __forceinline__ unsigned short f2b(float f) {
    __hip_bfloat16 h = __float2bfloat16(f);
    return *(unsigned short*)&h;
}

// Convert 8 bf16 (4 dwords) -> 4 float2 pairs. Pair k = {elem 2k, elem 2k+1}:
// lo = dword<<16, hi = dword&0xFFFF0000 (1 instr per float, same as scalar).
static __device__ __forceinline__ void b2f2(const u16x8& u, f32x2* out) {
    const unsigned* d = (const unsigned*)&u;
#pragma unroll
    for (int k = 0; k < 4; k++) {
        f32x2 t;
        t.x = __uint_as_float(d[k] << 16);
        t.y = __uint_as_float(d[k] & 0xFFFF0000u);
        out[k] = t;
    }
}

// Sum across each 16-lane row via DPP (no LDS/DS-pipe ops, no extra VGPR).
// Stages: quad_perm[1,0,3,2] (xor1), quad_perm[2,3,0,1] (xor2) -> quad sums;
// row_ror:4 + row_ror:8 -> sum of the 4 quad-sums. All 16 lanes get the total.
static __device__ __forceinline__ float red16(float p) {
    float t;
    t = __int_as_float(__builtin_amdgcn_update_dpp(
            0, __float_as_int(p), 0xB1, 0xF, 0xF, true));   // quad_perm xor1
    p += t;
    t = __int_as_float(__builtin_amdgcn_update_dpp(
            0, __float_as_int(p), 0x4E, 0xF, 0xF, true));   // quad_perm xor2
    p += t;
    t = __int_as_float(__builtin_amdgcn_update_dpp(
            0, __float_as_int(p), 0x124, 0xF, 0xF, true));  // row_ror:4
    p += t;
    t = __int_as_float(__builtin_amdgcn_update_dpp(
            0, __float_as_int(p), 0x128, 0xF, 0xF, true));  // row_ror:8
    p += t;
    return p;
}

// ---------------- consolidated init: zeros + weight packs + feature build ---

__global__ __launch_bounds__(256) void prep_init(
    int* __restrict__ degcnt, int n_degcnt,
    int* __restrict__ outz, int n_out,
    const float* __restrict__ Wl2, const float* __restrict__ Wr2,
    __hip_bfloat16* __restrict__ Wp,
    const float* __restrict__ Wl1, const float* __restrict__ Wr1,
    __hip_bfloat16* __restrict__ Wp1,
    const int* __restrict__ atom_num, const int* __restrict__ atom_arom,
    const float* __restrict__ x_cont, const float* __restrict__ atom_emb,
    const float* __restrict__ bool_emb, __hip_bfloat16* __restrict__ Xf, int N,
    int e_z1, int e_z2, int e_pw, int e_pw1)   // exclusive block-range ends
{
    int b = blockIdx.x;
    if (b < e_z1) {                       // zero degcnt
        int i = b * 256 + threadIdx.x;
        if (i < n_degcnt) degcnt[i] = 0;
    } else if (b < e_z2) {                // zero out
        int i = (b - e_z1) * 256 + threadIdx.x;
        if (i < n_out) outz[i] = 0;
    } else if (b < e_pw) {                // pack W2 (32768 frags)
        int idx = (b - e_z2) * 256 + threadIdx.x;
        int j    = idx & 7;
        int lane = (idx >> 3) & 63;
        int ks   = (idx >> 9) & 3;
        int nt   = idx >> 11;
        int k = ks * 32 + ((lane >> 4) << 3) + j;
        int n = nt * 16 + (lane & 15);
        float v = (n < 128) ? Wl2[k * 128 + n] : Wr2[k * 128 + (n - 128)];
        Wp[idx] = __float2bfloat16(v);
    } else if (b < e_pw1) {               // pack W1 (8192 frags, K pad 26->32)
        int idx = (b - e_pw) * 256 + threadIdx.x;
        int j    = idx & 7;
        int lane = (idx >> 3) & 63;
        int ntc  = idx >> 9;
        int k = ((lane >> 4) << 3) + j;
        int n = ntc * 16 + (lane & 15);
        float v = 0.f;
        if (k < 26) v = (n < 128) ? Wl1[k * 128 + n] : Wr1[k * 128 + (n - 128)];
        Wp1[idx] = __float2bfloat16(v);
    } else {                              // build Xf[N][32]
        int n = (b - e_pw1) * 256 + threadIdx.x;
        if (n >= N) return;
        int an = atom_num[n], am = atom_arom[n];
        unsigned short v[32];
#pragma unroll
        for (int k = 0; k < 16; k++) v[k] = f2b(atom_emb[an * 16 + k]);
#pragma unroll
        for (int k = 0; k < 8; k++)  v[16 + k] = f2b(x_cont[(size_t)n * 8 + k]);
        v[24] = f2b(bool_emb[am * 2]);
        v[25] = f2b(bool_emb[am * 2 + 1]);
#pragma unroll
        for (int k = 26; k < 32; k++) v[k] = 0;
        unsigned short* dst = (unsigned short*)Xf + (size_t)n * 32;
#pragma unroll
        for (int q = 0; q < 4; q++)
            *(u16x8*)(dst + q * 8) = *(const u16x8*)&v[q * 8];
    }
}

// ---------------- prep kernels ----------------

__global__ __launch_bounds__(256) void count_deg(
    const int* __restrict__ dst, int* __restrict__ deg, int E)
{
    int e = blockIdx.x * 256 + threadIdx.x;
    if (e < E) atomicAdd(&deg[dst[e]], 1);
}

// ---- degree counting sort (contention-free) + sorted-CSR layout ----
#define SORT_BLK 1024

__global__ __launch_bounds__(256) void sort_hist(
    const int* __restrict__ deg, int* __restrict__ block_hist, int N)
{
    __shared__ int h[512];
    for (int i = threadIdx.x; i < 512; i += 256) h[i] = 0;
    __syncthreads();
    int base = blockIdx.x * SORT_BLK;
#pragma unroll
    for (int k = 0; k < 4; k++) {
        int n = base + k * 256 + threadIdx.x;
        if (n < N) {
            int d = deg[n]; if (d > 511) d = 511;
            atomicAdd(&h[d], 1);              // LDS atomic, block-local
        }
    }
    __syncthreads();
    for (int i = threadIdx.x; i < 512; i += 256)
        block_hist[blockIdx.x * 512 + i] = h[i];
}

// One block, 512 threads: thread t owns bin t. Column-scan across sort blocks
// (block_hist -> per-block exclusive offsets), then two bin scans:
// bin_base[d] (node positions) and edge_base[d] (edge positions, weight d).
// R19b: column scan batched 4-wide -> 4 loads in flight instead of a serial
// load->add->load chain (single-block kernel, latency-bound).
__global__ __launch_bounds__(512) void sort_scan(
    int* __restrict__ block_hist, int* __restrict__ bin_base,
    int* __restrict__ edge_base, int nsb)
{
    __shared__ int s[512];
    int t = threadIdx.x;
    int acc = 0;
    int b = 0;
    for (; b + 4 <= nsb; b += 4) {
        int v0 = block_hist[(b + 0) * 512 + t];
        int v1 = block_hist[(b + 1) * 512 + t];
        int v2 = block_hist[(b + 2) * 512 + t];
        int v3 = block_hist[(b + 3) * 512 + t];
        block_hist[(b + 0) * 512 + t] = acc; acc += v0;
        block_hist[(b + 1) * 512 + t] = acc; acc += v1;
        block_hist[(b + 2) * 512 + t] = acc; acc += v2;
        block_hist[(b + 3) * 512 + t] = acc; acc += v3;
    }
    for (; b < nsb; b++) {
        int v = block_hist[b * 512 + t];
        block_hist[b * 512 + t] = acc;
        acc += v;
    }
    // scan 1: node counts -> bin_base
    s[t] = acc;
    __syncthreads();
    for (int off = 1; off < 512; off <<= 1) {
        int x = (t >= off) ? s[t - off] : 0;
        __syncthreads();
        s[t] += x;
        __syncthreads();
    }
    bin_base[t] = s[t] - acc;
    __syncthreads();
    // scan 2: edge counts (count*d) -> edge_base
    int ec = acc * t;
    s[t] = ec;
    __syncthreads();
    for (int off = 1; off < 512; off <<= 1) {
        int x = (t >= off) ? s[t - off] : 0;
        __syncthreads();
        s[t] += x;
        __syncthreads();
    }
    edge_base[t] = s[t] - ec;
}

// Scatter: meta[pos] = {rp_sorted, deg, node, 0}; nrp[node] = rp_sorted.
__global__ __launch_bounds__(256) void sort_scatter(
    const int* __restrict__ deg, const int* __restrict__ block_hist,
    const int* __restrict__ bin_base, const int* __restrict__ edge_base,
    int4* __restrict__ meta, int* __restrict__ nrp, int N)
{
    __shared__ int h[512];
    for (int i = threadIdx.x; i < 512; i += 256) h[i] = 0;
    __syncthreads();
    int bs = blockIdx.x;
    int base = bs * SORT_BLK;
#pragma unroll
    for (int k = 0; k < 4; k++) {
        int n = base + k * 256 + threadIdx.x;
        if (n < N) {
            int d = deg[n]; if (d > 511) d = 511;
            int r = atomicAdd(&h[d], 1);      // LDS atomic rank
            int posInBin = block_hist[bs * 512 + d] + r;
            int pos = bin_base[d] + posInBin;
            int rp = edge_base[d] + posInBin * d;
            int4 m; m.x = rp; m.y = d; m.z = n; m.w = 0;
            meta[pos] = m;
            nrp[n] = rp;
        }
    }
}

// Fill sorted CSR with PACKED per-slot records {src, codes, ec_bits, 0}.
__global__ __launch_bounds__(256) void csr_fill(
    const int* __restrict__ src, const int* __restrict__ dst,
    const int* __restrict__ bond_type, const float* __restrict__ edge_cont,
    const int* __restrict__ bond_conj, const int* __restrict__ bond_arom,
    const int* __restrict__ nrp, int* __restrict__ cnt,
    int4* __restrict__ csr_rec, int E)
{
    int e = blockIdx.x * 256 + threadIdx.x;
    if (e >= E) return;
    int d = dst[e];
    int pos = nrp[d] + atomicAdd(&cnt[d], 1);
    int codes = (bond_type[e] & 0xFF) | ((bond_conj[e] & 1) << 8) | ((bond_arom[e] & 1) << 16);
    int4 rec;
    rec.x = src[e];
    rec.y = codes;
    rec.z = __float_as_int(edge_cont[e]);
    rec.w = 0;
    csr_rec[pos] = rec;
}

// ---------------- per-layer kernels ----------------

// Layer-1 GEMM via MFMA, K=32 (single step): Xfeat[N][32] @ Wp1 -> XL|XR.
__global__ __launch_bounds__(256) void gemm_mfma1(
    const __hip_bfloat16* __restrict__ Xf,   // [N][32]
    const __hip_bfloat16* __restrict__ Wp,   // packed frags, 8192 bf16
    const float* __restrict__ bl, const float* __restrict__ br,
    __hip_bfloat16* __restrict__ XL, __hip_bfloat16* __restrict__ XR, int N)
{
    __shared__ unsigned short sT[64 * 256];   // 32 KB output tile
    int lane = threadIdx.x & 63;
    int wave = threadIdx.x >> 6;
    int row0 = blockIdx.x * 64;
    int m_lane = lane & 15;
    int quad = lane >> 4;
    const unsigned short* Xu = (const unsigned short*)Xf;
    const unsigned short* Wu = (const unsigned short*)Wp;

    f32x4 acc[4][4];
#pragma unroll
    for (int mt = 0; mt < 4; mt++)
#pragma unroll
        for (int nt = 0; nt < 4; nt++) acc[mt][nt] = (f32x4){0.f, 0.f, 0.f, 0.f};

    bf16x8 a[4], b[4];
#pragma unroll
    for (int mt = 0; mt < 4; mt++)
        a[mt] = *(const bf16x8*)(Xu + (size_t)(row0 + mt * 16 + m_lane) * 32 + quad * 8);
#pragma unroll
    for (int nt = 0; nt < 4; nt++)
        b[nt] = *(const bf16x8*)(Wu + ((wave * 4 + nt) * 64 + lane) * 8);
#pragma unroll
    for (int mt = 0; mt < 4; mt++)
#pragma unroll
        for (int nt = 0; nt < 4; nt++)
            acc[mt][nt] = __builtin_amdgcn_mfma_f32_16x16x32_bf16(
                a[mt], b[nt], acc[mt][nt], 0, 0, 0);

#pragma unroll
    for (int nt = 0; nt < 4; nt++) {
        int col = wave * 64 + nt * 16 + m_lane;
        float bv = (col < 128) ? bl[col] : br[col - 128];
#pragma unroll
        for (int mt = 0; mt < 4; mt++) {
            int rbase = mt * 16 + quad * 4;
#pragma unroll
            for (int reg = 0; reg < 4; reg++)
                sT[(rbase + reg) * 256 + col] = f2b(acc[mt][nt][reg] + bv);
        }
    }

    __syncthreads();

    unsigned short* XLu = (unsigned short*)XL;
    unsigned short* XRu = (unsigned short*)XR;
    int t = threadIdx.x;
#pragma unroll
    for (int q = 0; q < 4; q++) {
        int s = t * 32 + q * 8;
        int r = s >> 7, c = s & 127;
        *(u16x8*)(XLu + (size_t)(row0 + r) * 128 + c) = *(const u16x8*)&sT[r * 256 + c];
        *(u16x8*)(XRu + (size_t)(row0 + r) * 128 + c) = *(const u16x8*)&sT[r * 256 + 128 + c];
    }
}

// Layers 2/3 GEMM via MFMA (K=128) with LDS-staged coalesced epilogue.
__global__ __launch_bounds__(256) void gemm_mfma(
    const __hip_bfloat16* H,               // [N][128]  (aliases XR)
    const __hip_bfloat16* __restrict__ Wp, // packed frags, 32768 bf16
    const float* __restrict__ bl, const float* __restrict__ br,
    __hip_bfloat16* __restrict__ XL, __hip_bfloat16* XR, int N)
{
    __shared__ unsigned short sT[64 * 256];   // 32 KB output tile
    int lane = threadIdx.x & 63;
    int wave = threadIdx.x >> 6;
    int row0 = blockIdx.x * 64;
    int m_lane = lane & 15;
    int quad = lane >> 4;
    const unsigned short* Hu = (const unsigned short*)H;
    const unsigned short* Wu = (const unsigned short*)Wp;

    f32x4 acc[4][4];
#pragma unroll
    for (int mt = 0; mt < 4; mt++)
#pragma unroll
        for (int nt = 0; nt < 4; nt++) acc[mt][nt] = (f32x4){0.f, 0.f, 0.f, 0.f};

#pragma unroll
    for (int ks = 0; ks < 4; ks++) {
        int koff = ks * 32 + quad * 8;
        bf16x8 a[4], b[4];
#pragma unroll
        for (int mt = 0; mt < 4; mt++)
            a[mt] = *(const bf16x8*)(Hu + (size_t)(row0 + mt * 16 + m_lane) * 128 + koff);
#pragma unroll
        for (int nt = 0; nt < 4; nt++)
            b[nt] = *(const bf16x8*)(Wu + ((((wave * 4 + nt) * 4) + ks) * 64 + lane) * 8);
#pragma unroll
        for (int mt = 0; mt < 4; mt++)
#pragma unroll
            for (int nt = 0; nt < 4; nt++)
                acc[mt][nt] = __builtin_amdgcn_mfma_f32_16x16x32_bf16(
                    a[mt], b[nt], acc[mt][nt], 0, 0, 0);
    }

#pragma unroll
    for (int nt = 0; nt < 4; nt++) {
        int col = wave * 64 + nt * 16 + m_lane;
        float bv = (col < 128) ? bl[col] : br[col - 128];
#pragma unroll
        for (int mt = 0; mt < 4; mt++) {
            int rbase = mt * 16 + quad * 4;
#pragma unroll
            for (int reg = 0; reg < 4; reg++)
                sT[(rbase + reg) * 256 + col] = f2b(acc[mt][nt][reg] + bv);
        }
    }

    __syncthreads();   // also drains all H loads before any XR store

    unsigned short* XLu = (unsigned short*)XL;
    unsigned short* XRu = (unsigned short*)XR;
    int t = threadIdx.x;
#pragma unroll
    for (int q = 0; q < 4; q++) {
        int s = t * 32 + q * 8;            // short index within 64x128 tile
        int r = s >> 7, c = s & 127;
        *(u16x8*)(XLu + (size_t)(row0 + r) * 128 + c) = *(const u16x8*)&sT[r * 256 + c];
        *(u16x8*)(XRu + (size_t)(row0 + r) * 128 + c) = *(const u16x8*)&sT[r * 256 + 128 + c];
    }
}

// FUSED logits + softmax + aggregate. 16-lane sub-waves, 4 nodes/wave.
// R27 pk-f32 column math. R30: template<bool POOL> — POOL=false is exactly
// the R27 kernel (compile-time dead args); POOL=true (layer 3) skips the
// OUT store and issues 8 no-return atomicMax into pool_out[batch[n]].
template<bool POOL>
__global__ __launch_bounds__(256) void gat_fused(
    const int4* __restrict__ meta, const int4* __restrict__ csr_rec,
    const float* __restrict__ bond_emb, const float* __restrict__ bool_emb,
    const __hip_bfloat16* __restrict__ XL, const __hip_bfloat16* XR,
    const float* __restrict__ We,        // [13][128]
    const float* __restrict__ att,       // [128]
    const float* __restrict__ bias,      // [128]
    __hip_bfloat16* OUT,
    const int* __restrict__ batch,       // node -> graph (POOL only)
    float* pool_out,                     // POOL only
    int N)
{
    __shared__ float sTbt[22 * TBT_S];   // bond_emb[bt] @ We[0:8], padded stride
    __shared__ float sTca[4 * TBT_S];    // bool-pair terms
    __shared__ float sW8[128];           // We[8,:]

    for (int i = threadIdx.x; i < 22 * 128; i += 256) {
        int bt = i >> 7, c = i & 127;
        float s = 0.f;
#pragma unroll
        for (int k = 0; k < 8; k++) s = fmaf(bond_emb[bt * 8 + k], We[k * 128 + c], s);
        sTbt[bt * TBT_S + c] = s;
    }
    for (int i = threadIdx.x; i < 4 * 128; i += 256) {
        int idx = i >> 7, c = i & 127;
        int cj = idx >> 1, ar = idx & 1;
        float s = bool_emb[cj * 2]     * We[9 * 128 + c]
                + bool_emb[cj * 2 + 1] * We[10 * 128 + c]
                + bool_emb[ar * 2]     * We[11 * 128 + c]
                + bool_emb[ar * 2 + 1] * We[12 * 128 + c];
        sTca[idx * TBT_S + c] = s;
    }
    if (threadIdx.x < 128) sW8[threadIdx.x] = We[8 * 128 + threadIdx.x];
    __syncthreads();

    int lane = threadIdx.x & 63;
    int wave = threadIdx.x >> 6;
    int sl   = lane & 15;
    int sw   = lane >> 4;
    int cbase = sl * 8;

    f32x2 a82[4], bs82[4], w882[4];
    {
        float4 t0 = *(const float4*)&att[cbase],  t1 = *(const float4*)&att[cbase + 4];
        float4 u0 = *(const float4*)&bias[cbase], u1 = *(const float4*)&bias[cbase + 4];
        float4 v0 = *(const float4*)&sW8[cbase],  v1 = *(const float4*)&sW8[cbase + 4];
        a82[0] = (f32x2){t0.x, t0.y};  a82[1] = (f32x2){t0.z, t0.w};
        a82[2] = (f32x2){t1.x, t1.y};  a82[3] = (f32x2){t1.z, t1.w};
        bs82[0] = (f32x2){u0.x, u0.y}; bs82[1] = (f32x2){u0.z, u0.w};
        bs82[2] = (f32x2){u1.x, u1.y}; bs82[3] = (f32x2){u1.z, u1.w};
        w882[0] = (f32x2){v0.x, v0.y}; w882[1] = (f32x2){v0.z, v0.w};
        w882[2] = (f32x2){v1.x, v1.y}; w882[3] = (f32x2){v1.z, v1.w};
    }

    const unsigned short* XLu = (const unsigned short*)XL;
    const unsigned short* XRu = (const unsigned short*)XR;
    unsigned short* OUTu = (unsigned short*)OUT;
    int* pouti = (int*)pool_out;

    int group = (blockIdx.x * 4 + wave) * 4 + sw;   // global sub-wave id
    int stride = gridDim.x * 16;

    if (group >= N) return;

    // ---- pipeline prologue ----
    int4 mt  = meta[group];                               // node i
    int ni   = group + stride;
    int4 mtn = meta[(ni < N) ? ni : (N - 1)];             // node i+1
    int4 rc[4];                                           // recs for i, chunk 0
    {
        int rp0 = mt.x, dg0 = mt.y;
#pragma unroll
        for (int jj = 0; jj < 4; jj++)
            rc[jj] = csr_rec[rp0 + (jj < dg0 ? jj : 0)];  // clamped: always valid
    }

    for (int idx = group; idx < N; idx += stride) {
        const int rp = mt.x, dg = mt.y, n = mt.z;

        // independent long-latency issues at iteration top:
        u16x8 uxr = *(const u16x8*)(XRu + (size_t)n * 128 + cbase);     // own XR
        u16x8 un  = *(const u16x8*)(XLu + (size_t)n * 128 + cbase);     // self XL
        int i2 = idx + 2 * stride;
        int4 mt2 = meta[(i2 < N) ? i2 : (N - 1)];                       // node i+2
        int gb = 0;
        if constexpr (POOL) gb = batch[n];                              // graph id

        f32x2 xr2[4];
        b2f2(uxr, xr2);

        float runs = 0.f;
        f32x2 acc2[4], ets2[4];
#pragma unroll
        for (int i = 0; i < 4; i++) {
            acc2[i] = (f32x2){0.f, 0.f};
            ets2[i] = (f32x2){0.f, 0.f};
        }

        int j = 0;
        do {   // runs once even for dg==0 (cnt=0) so rc advances to next node
            int cnt = dg - j;
            cnt = cnt < 0 ? 0 : (cnt > 4 ? 4 : cnt);

            // uv gathers issue NOW from prefetched records (one memory round);
            // GUARDED (R24: unconditional clamped loads lengthen vmcnt drain)
            u16x8 uv[4];
#pragma unroll
            for (int jj = 0; jj < 4; jj++)
                if (jj < cnt)
                    uv[jj] = *(const u16x8*)(XLu + (size_t)rc[jj].x * 128 + cbase);

            // prefetch next chunk: in-node j+4, else next node's first chunk
            // (mtn is register-resident thanks to the 2-deep meta pipeline)
            int innode = (j + 4 < dg);
            int nb = innode ? (rp + j + 4) : mtn.x;
            int nd = innode ? (dg - j - 4) : mtn.y;
            int4 rn[4];
#pragma unroll
            for (int jj = 0; jj < 4; jj++)
                rn[jj] = csr_rec[nb + (jj < nd ? jj : 0)];   // clamped: valid

            // merged per-edge phase (R26), packed-f32 column math (R27).
#pragma unroll
            for (int jj = 0; jj < 4; jj++) {
                if (jj >= cnt) continue;
                int bt = rc[jj].y & 0xFF;
                int ca = (((rc[jj].y >> 8) & 1) << 1) | ((rc[jj].y >> 16) & 1);
                float ec = __int_as_float(rc[jj].z);
                const f32x2* tb = (const f32x2*)&sTbt[bt * TBT_S + cbase];
                const f32x2* tc = (const f32x2*)&sTca[ca * TBT_S + cbase];
                f32x2 uvf[4];
                b2f2(uv[jj], uvf);
                f32x2 ec2 = (f32x2){ec, ec};
                f32x2 ps = (f32x2){0.f, 0.f};
#pragma unroll
                for (int i = 0; i < 4; i++) {
                    f32x2 et = __builtin_elementwise_fma(ec2, w882[i], tb[i] + tc[i]);
                    ets2[i] += et;
                    f32x2 v = xr2[i] + uvf[i] + et;
                    f32x2 m = __builtin_elementwise_max(v, 0.2f * v);  // leaky 0.2
                    ps = __builtin_elementwise_fma(m, a82[i], ps);
                }
                float p = red16(ps.x + ps.y);  // DPP reduce, no DS ops
                float wgt = __expf(p);
                runs += wgt;
                f32x2 w2 = (f32x2){wgt, wgt};
#pragma unroll
                for (int i = 0; i < 4; i++)
                    acc2[i] = __builtin_elementwise_fma(w2, uvf[i], acc2[i]);
            }
#pragma unroll
            for (int jj = 0; jj < 4; jj++) rc[jj] = rn[jj];
            j += 4;
        } while (j < dg);

        {   // self loop (un in flight since iteration top)
            float invd = 1.f / (float)(dg > 0 ? dg : 1);
            f32x2 iv2 = (f32x2){invd, invd};
            f32x2 unf[4];
            b2f2(un, unf);
            f32x2 ps = (f32x2){0.f, 0.f};
#pragma unroll
            for (int i = 0; i < 4; i++) {
                f32x2 v = __builtin_elementwise_fma(ets2[i], iv2, xr2[i] + unf[i]);
                f32x2 m = __builtin_elementwise_max(v, 0.2f * v);
                ps = __builtin_elementwise_fma(m, a82[i], ps);
            }
            float p = red16(ps.x + ps.y);
            float wgt = __expf(p);
            runs += wgt;
            f32x2 w2 = (f32x2){wgt, wgt};
#pragma unroll
            for (int i = 0; i < 4; i++)
                acc2[i] = __builtin_elementwise_fma(w2, unf[i], acc2[i]);
        }

        float inv = 1.f / runs;
        f32x2 iv2 = (f32x2){inv, inv};
        if constexpr (POOL) {
            // fused pool: 8 no-return atomicMax (values >= 0; out pre-zeroed)
            int* og = pouti + (size_t)gb * 128 + cbase;
#pragma unroll
            for (int i = 0; i < 4; i++) {
                f32x2 r = __builtin_elementwise_fma(acc2[i], iv2, bs82[i]);
                f32x2 z = (f32x2){0.f, 0.f};
                r = __builtin_elementwise_max(r, z);   // ReLU
                atomicMax(og + 2 * i,     __float_as_int(r.x));
                atomicMax(og + 2 * i + 1, __float_as_int(r.y));
            }
        } else {
            u16x8 o;
#pragma unroll
            for (int i = 0; i < 4; i++) {
                f32x2 r = __builtin_elementwise_fma(acc2[i], iv2, bs82[i]);
                f32x2 z = (f32x2){0.f, 0.f};
                r = __builtin_elementwise_max(r, z);   // ReLU
                o[2 * i]     = f2b(r.x);
                o[2 * i + 1] = f2b(r.y);
            }
            *(u16x8*)(OUTu + (size_t)n * 128 + cbase) = o;
        }

        // rotate meta pipeline
        mt = mtn; mtn = mt2;
    }
}

// ---------------------------------------------------------------------------

static inline size_t align_up(size_t x, size_t a) { return (x + a - 1) & ~(a - 1); }
static inline int cdiv(int a, int b) { return (a + b - 1) / b; }

extern "C" void kernel_launch(void* const* d_in, const int* in_sizes, int n_in,
                              void* d_out, int out_size, void* d_ws, size_t ws_size,
                              hipStream_t stream)
{
    const int N = in_sizes[0];          // 200000 (multiple of 64)
    const int E = in_sizes[3];          // 800000

    const int*   atom_num  = (const int*)d_in[0];
    const int*   atom_arom = (const int*)d_in[1];
    const float* x_cont    = (const float*)d_in[2];
    const int*   bond_type = (const int*)d_in[3];
    const float* edge_cont = (const float*)d_in[4];
    const int*   bond_conj = (const int*)d_in[5];
    const int*   bond_arom = (const int*)d_in[6];
    const int*   e_src     = (const int*)d_in[7];
    const int*   e_dst     = e_src + E;
    const int*   batch     = (const int*)d_in[8];
    const float* atom_emb  = (const float*)d_in[9];
    const float* bond_emb  = (const float*)d_in[10];
    const float* bool_emb  = (const float*)d_in[11];
    const float* Wl1 = (const float*)d_in[12]; const float* bl1 = (const float*)d_in[13];
    const float* Wr1 = (const float*)d_in[14]; const float* br1 = (const float*)d_in[15];
    const float* We1 = (const float*)d_in[16]; const float* att1 = (const float*)d_in[17];
    const float* bias1 = (const float*)d_in[18];
    const float* Wl2 = (const float*)d_in[19]; const float* bl2 = (const float*)d_in[20];
    const float* Wr2 = (const float*)d_in[21]; const float* br2 = (const float*)d_in[22];
    const float* We2 = (const float*)d_in[23]; const float* att2 = (const float*)d_in[24];
    const float* bias2 = (const float*)d_in[25];
    float* out = (float*)d_out;

    const int nsb = cdiv(N, SORT_BLK);  // sort blocks (196)

    // ---- workspace layout (~125 MB; ws_size is 256 MB) ----
    char* w = (char*)d_ws;
    size_t off = 0;
    auto alloc = [&](size_t bytes) {
        void* p = w + off;
        off = align_up(off + bytes, 256);
        return p;
    };
    __hip_bfloat16* A  = (__hip_bfloat16*)alloc((size_t)N * 128 * 2);   // XL
    __hip_bfloat16* B  = (__hip_bfloat16*)alloc((size_t)N * 128 * 2);   // XR / H
    __hip_bfloat16* Xf = (__hip_bfloat16*)alloc((size_t)N * 32 * 2);    // layer-1 feats
    __hip_bfloat16* Wp = (__hip_bfloat16*)alloc((size_t)32768 * 2);     // packed W2
    __hip_bfloat16* Wp1= (__hip_bfloat16*)alloc((size_t)8192 * 2);      // packed W1
    int*   degcnt  = (int*)alloc((size_t)2 * N * 4);
    int*   deg     = degcnt;
    int*   cnt     = degcnt + N;
    int4*  csr_rec = (int4*)alloc((size_t)E * 16);
    int4*  meta    = (int4*)alloc((size_t)N * 16);
    int*   nrp     = (int*)alloc((size_t)N * 4);
    int*   block_hist = (int*)alloc((size_t)nsb * 512 * 4);
    int*   bin_base   = (int*)alloc(512 * 4);
    int*   edge_base  = (int*)alloc(512 * 4);
    size_t required = off;

    fprintf(stderr, "[GNN] ws_size=%zu required=%zu%s\n", ws_size, required,
            ws_size < required ? "  INSUFFICIENT - skipping" : "");
    if (ws_size < required) return;

    // ---- consolidated init (zeros + packs + feature build), one dispatch ----
    int bz1 = cdiv(2 * N, 256);
    int bz2 = cdiv(out_size, 256);
    int bpw = 32768 / 256;
    int bpw1 = 8192 / 256;
    int bbx = cdiv(N, 256);
    int e_z1 = bz1, e_z2 = e_z1 + bz2, e_pw = e_z2 + bpw, e_pw1 = e_pw + bpw1;
    prep_init<<<e_pw1 + bbx, 256, 0, stream>>>(
        degcnt, 2 * N, (int*)out, out_size,
        Wl2, Wr2, Wp, Wl1, Wr1, Wp1,
        atom_num, atom_arom, x_cont, atom_emb, bool_emb, Xf, N,
        e_z1, e_z2, e_pw, e_pw1);

    // ---- prep: degree sort + sorted CSR (5 dispatches after prep_init) ----
    count_deg<<<cdiv(E, 256), 256, 0, stream>>>(e_dst, deg, E);
    sort_hist<<<nsb, 256, 0, stream>>>(deg, block_hist, N);
    sort_scan<<<1, 512, 0, stream>>>(block_hist, bin_base, edge_base, nsb);
    sort_scatter<<<nsb, 256, 0, stream>>>(deg, block_hist, bin_base, edge_base,
                                          meta, nrp, N);
    csr_fill<<<cdiv(E, 256), 256, 0, stream>>>(e_src, e_dst, bond_type, edge_cont,
                                               bond_conj, bond_arom, nrp, cnt,
                                               csr_rec, E);

    // R26/R27: proven geometry.
    const int fused_blocks = 1536;

    // ---- layer 1: Xf -> A(XL), B(XR) via MFMA; fused -> B(H1) ----
    gemm_mfma1<<<N / 64, 256, 0, stream>>>(Xf, Wp1, bl1, br1, A, B, N);
    gat_fused<false><<<fused_blocks, 256, 0, stream>>>(
        meta, csr_rec, bond_emb, bool_emb, A, B, We1, att1, bias1, B,
        nullptr, nullptr, N);

    // ---- layer 2: B -> A, B(in-place); fused -> B(H2) ----
    gemm_mfma<<<N / 64, 256, 0, stream>>>(B, Wp, bl2, br2, A, B, N);
    gat_fused<false><<<fused_blocks, 256, 0, stream>>>(
        meta, csr_rec, bond_emb, bool_emb, A, B, We2, att2, bias2, B,
        nullptr, nullptr, N);

    // ---- layer 3 with FUSED global max pool into d_out (R30, POOL=true) ----
    gemm_mfma<<<N / 64, 256, 0, stream>>>(B, Wp, bl2, br2, A, B, N);
    gat_fused<true><<<fused_blocks, 256, 0, stream>>>(
        meta, csr_rec, bond_emb, bool_emb, A, B, We2, att2, bias2, B,
        batch, out, N);
}

// Round 13
// 593.484 us; speedup vs baseline: 1.9731x; 1.9320x over previous
//
#include <hip/hip_runtime.h>
#include <hip/hip_bf16.h>
#include <cstdint>
#include <cstdio>

// ---------------------------------------------------------------------------
// GATv2 x3 (shared weights layers 2,3) + global max pool, MI355X.
// R31: EXACT REVERT to R27 (proven 596us total; gat 68.3us, pool separate).
//   R28/R29/R30 post-mortem (three pool experiments, all regressions, all
//   the same root error): fused per-node pooling needs 128 atomics/node
//   (every column maxes into the graph row) = 25.6M device-scope atomicMax
//   = 800MB of RMW traffic = ~650us. Grid-stride order is degree-sorted,
//   not batch-sorted => no thread-local accumulation possible in gat.
//   The SEPARATE pool over batch-ordered H is structurally right: 1 col/
//   thread, serial 64-node run, atomic only at graph boundaries (~1.6M
//   atomics). R28's "vectorize the pool loads" made it worse because each
//   flush then cost 8 atomics (7.7M total) — the currency is atomic count,
//   not load width (the 128-consecutive-u16 row read was already a fully
//   coalesced 256B/wave).
// R27 (kept): pk-f32 column math. R26 (kept): merged per-edge phase.
// R22 (kept): DPP red16. R20 (kept): rc/rn double-buffer + 2-deep meta +
//   hoists + guarded uv loads (R24). R19b (kept): sort_scan 4-wide.
//   Grid 1536 (proven; 1024 regressed in R23).
//
// Sorted-CSR (R15): meta[idx]={rp,deg,node} coalesced; recs contiguous at rp.
// Buffers: A = XL, B = XR / H (rotating), both [N][128] bf16.
//   gemm_mfma (K=128): reads H=B rows, writes XL=A + XR=B IN-PLACE (own 64
//     rows; __syncthreads between reads and stores).
// ws ~125 MB (budget 256 MB, checked). No hipMemset* (graph capture).
// ---------------------------------------------------------------------------

typedef __attribute__((ext_vector_type(8))) short bf16x8;           // MFMA frag
typedef __attribute__((ext_vector_type(8))) unsigned short u16x8;   // 16B row chunk
typedef __attribute__((ext_vector_type(4))) float f32x4;
typedef __attribute__((ext_vector_type(2))) float f32x2;            // pk-f32 pair

#define TBT_S 132   // padded LDS table stride (bank spread)

static __device__ __forceinline__ float b2f(unsigned short u) {
    return __uint_as_float(((unsigned)u) << 16);
}
static __device__ __forceinline__ unsigned short f2b(float f) {
    __hip_bfloat16 h = __float2bfloat16(f);
    return *(unsigned short*)&h;
}

// Convert 8 bf16 (4 dwords) -> 4 float2 pairs. Pair k = {elem 2k, elem 2k+1}:
// lo = dword<<16, hi = dword&0xFFFF0000 (1 instr per float, same as scalar).
static __device__ __forceinline__ void b2f2(const u16x8& u, f32x2* out) {
    const unsigned* d = (const unsigned*)&u;
#pragma unroll
    for (int k = 0; k < 4; k++) {
        f32x2 t;
        t.x = __uint_as_float(d[k] << 16);
        t.y = __uint_as_float(d[k] & 0xFFFF0000u);
        out[k] = t;
    }
}

// Sum across each 16-lane row via DPP (no LDS/DS-pipe ops, no extra VGPR).
// Stages: quad_perm[1,0,3,2] (xor1), quad_perm[2,3,0,1] (xor2) -> quad sums;
// row_ror:4 + row_ror:8 -> sum of the 4 quad-sums. All 16 lanes get the total.
static __device__ __forceinline__ float red16(float p) {
    float t;
    t = __int_as_float(__builtin_amdgcn_update_dpp(
            0, __float_as_int(p), 0xB1, 0xF, 0xF, true));   // quad_perm xor1
    p += t;
    t = __int_as_float(__builtin_amdgcn_update_dpp(
            0, __float_as_int(p), 0x4E, 0xF, 0xF, true));   // quad_perm xor2
    p += t;
    t = __int_as_float(__builtin_amdgcn_update_dpp(
            0, __float_as_int(p), 0x124, 0xF, 0xF, true));  // row_ror:4
    p += t;
    t = __int_as_float(__builtin_amdgcn_update_dpp(
            0, __float_as_int(p), 0x128, 0xF, 0xF, true));  // row_ror:8
    p += t;
    return p;
}

// ---------------- consolidated init: zeros + weight packs + feature build ---

__global__ __launch_bounds__(256) void prep_init(
    int* __restrict__ degcnt, int n_degcnt,
    int* __restrict__ outz, int n_out,
    const float* __restrict__ Wl2, const float* __restrict__ Wr2,
    __hip_bfloat16* __restrict__ Wp,
    const float* __restrict__ Wl1, const float* __restrict__ Wr1,
    __hip_bfloat16* __restrict__ Wp1,
    const int* __restrict__ atom_num, const int* __restrict__ atom_arom,
    const float* __restrict__ x_cont, const float* __restrict__ atom_emb,
    const float* __restrict__ bool_emb, __hip_bfloat16* __restrict__ Xf, int N,
    int e_z1, int e_z2, int e_pw, int e_pw1)   // exclusive block-range ends
{
    int b = blockIdx.x;
    if (b < e_z1) {                       // zero degcnt
        int i = b * 256 + threadIdx.x;
        if (i < n_degcnt) degcnt[i] = 0;
    } else if (b < e_z2) {                // zero out
        int i = (b - e_z1) * 256 + threadIdx.x;
        if (i < n_out) outz[i] = 0;
    } else if (b < e_pw) {                // pack W2 (32768 frags)
        int idx = (b - e_z2) * 256 + threadIdx.x;
        int j    = idx & 7;
        int lane = (idx >> 3) & 63;
        int ks   = (idx >> 9) & 3;
        int nt   = idx >> 11;
        int k = ks * 32 + ((lane >> 4) << 3) + j;
        int n = nt * 16 + (lane & 15);
        float v = (n < 128) ? Wl2[k * 128 + n] : Wr2[k * 128 + (n - 128)];
        Wp[idx] = __float2bfloat16(v);
    } else if (b < e_pw1) {               // pack W1 (8192 frags, K pad 26->32)
        int idx = (b - e_pw) * 256 + threadIdx.x;
        int j    = idx & 7;
        int lane = (idx >> 3) & 63;
        int ntc  = idx >> 9;
        int k = ((lane >> 4) << 3) + j;
        int n = ntc * 16 + (lane & 15);
        float v = 0.f;
        if (k < 26) v = (n < 128) ? Wl1[k * 128 + n] : Wr1[k * 128 + (n - 128)];
        Wp1[idx] = __float2bfloat16(v);
    } else {                              // build Xf[N][32]
        int n = (b - e_pw1) * 256 + threadIdx.x;
        if (n >= N) return;
        int an = atom_num[n], am = atom_arom[n];
        unsigned short v[32];
#pragma unroll
        for (int k = 0; k < 16; k++) v[k] = f2b(atom_emb[an * 16 + k]);
#pragma unroll
        for (int k = 0; k < 8; k++)  v[16 + k] = f2b(x_cont[(size_t)n * 8 + k]);
        v[24] = f2b(bool_emb[am * 2]);
        v[25] = f2b(bool_emb[am * 2 + 1]);
#pragma unroll
        for (int k = 26; k < 32; k++) v[k] = 0;
        unsigned short* dst = (unsigned short*)Xf + (size_t)n * 32;
#pragma unroll
        for (int q = 0; q < 4; q++)
            *(u16x8*)(dst + q * 8) = *(const u16x8*)&v[q * 8];
    }
}

// ---------------- prep kernels ----------------

__global__ __launch_bounds__(256) void count_deg(
    const int* __restrict__ dst, int* __restrict__ deg, int E)
{
    int e = blockIdx.x * 256 + threadIdx.x;
    if (e < E) atomicAdd(&deg[dst[e]], 1);
}

// ---- degree counting sort (contention-free) + sorted-CSR layout ----
#define SORT_BLK 1024

__global__ __launch_bounds__(256) void sort_hist(
    const int* __restrict__ deg, int* __restrict__ block_hist, int N)
{
    __shared__ int h[512];
    for (int i = threadIdx.x; i < 512; i += 256) h[i] = 0;
    __syncthreads();
    int base = blockIdx.x * SORT_BLK;
#pragma unroll
    for (int k = 0; k < 4; k++) {
        int n = base + k * 256 + threadIdx.x;
        if (n < N) {
            int d = deg[n]; if (d > 511) d = 511;
            atomicAdd(&h[d], 1);              // LDS atomic, block-local
        }
    }
    __syncthreads();
    for (int i = threadIdx.x; i < 512; i += 256)
        block_hist[blockIdx.x * 512 + i] = h[i];
}

// One block, 512 threads: thread t owns bin t. Column-scan across sort blocks
// (block_hist -> per-block exclusive offsets), then two bin scans:
// bin_base[d] (node positions) and edge_base[d] (edge positions, weight d).
// R19b: column scan batched 4-wide -> 4 loads in flight instead of a serial
// load->add->load chain (single-block kernel, latency-bound).
__global__ __launch_bounds__(512) void sort_scan(
    int* __restrict__ block_hist, int* __restrict__ bin_base,
    int* __restrict__ edge_base, int nsb)
{
    __shared__ int s[512];
    int t = threadIdx.x;
    int acc = 0;
    int b = 0;
    for (; b + 4 <= nsb; b += 4) {
        int v0 = block_hist[(b + 0) * 512 + t];
        int v1 = block_hist[(b + 1) * 512 + t];
        int v2 = block_hist[(b + 2) * 512 + t];
        int v3 = block_hist[(b + 3) * 512 + t];
        block_hist[(b + 0) * 512 + t] = acc; acc += v0;
        block_hist[(b + 1) * 512 + t] = acc; acc += v1;
        block_hist[(b + 2) * 512 + t] = acc; acc += v2;
        block_hist[(b + 3) * 512 + t] = acc; acc += v3;
    }
    for (; b < nsb; b++) {
        int v = block_hist[b * 512 + t];
        block_hist[b * 512 + t] = acc;
        acc += v;
    }
    // scan 1: node counts -> bin_base
    s[t] = acc;
    __syncthreads();
    for (int off = 1; off < 512; off <<= 1) {
        int x = (t >= off) ? s[t - off] : 0;
        __syncthreads();
        s[t] += x;
        __syncthreads();
    }
    bin_base[t] = s[t] - acc;
    __syncthreads();
    // scan 2: edge counts (count*d) -> edge_base
    int ec = acc * t;
    s[t] = ec;
    __syncthreads();
    for (int off = 1; off < 512; off <<= 1) {
        int x = (t >= off) ? s[t - off] : 0;
        __syncthreads();
        s[t] += x;
        __syncthreads();
    }
    edge_base[t] = s[t] - ec;
}

// Scatter: meta[pos] = {rp_sorted, deg, node, 0}; nrp[node] = rp_sorted.
__global__ __launch_bounds__(256) void sort_scatter(
    const int* __restrict__ deg, const int* __restrict__ block_hist,
    const int* __restrict__ bin_base, const int* __restrict__ edge_base,
    int4* __restrict__ meta, int* __restrict__ nrp, int N)
{
    __shared__ int h[512];
    for (int i = threadIdx.x; i < 512; i += 256) h[i] = 0;
    __syncthreads();
    int bs = blockIdx.x;
    int base = bs * SORT_BLK;
#pragma unroll
    for (int k = 0; k < 4; k++) {
        int n = base + k * 256 + threadIdx.x;
        if (n < N) {
            int d = deg[n]; if (d > 511) d = 511;
            int r = atomicAdd(&h[d], 1);      // LDS atomic rank
            int posInBin = block_hist[bs * 512 + d] + r;
            int pos = bin_base[d] + posInBin;
            int rp = edge_base[d] + posInBin * d;
            int4 m; m.x = rp; m.y = d; m.z = n; m.w = 0;
            meta[pos] = m;
            nrp[n] = rp;
        }
    }
}

// Fill sorted CSR with PACKED per-slot records {src, codes, ec_bits, 0}.
__global__ __launch_bounds__(256) void csr_fill(
    const int* __restrict__ src, const int* __restrict__ dst,
    const int* __restrict__ bond_type, const float* __restrict__ edge_cont,
    const int* __restrict__ bond_conj, const int* __restrict__ bond_arom,
    const int* __restrict__ nrp, int* __restrict__ cnt,
    int4* __restrict__ csr_rec, int E)
{
    int e = blockIdx.x * 256 + threadIdx.x;
    if (e >= E) return;
    int d = dst[e];
    int pos = nrp[d] + atomicAdd(&cnt[d], 1);
    int codes = (bond_type[e] & 0xFF) | ((bond_conj[e] & 1) << 8) | ((bond_arom[e] & 1) << 16);
    int4 rec;
    rec.x = src[e];
    rec.y = codes;
    rec.z = __float_as_int(edge_cont[e]);
    rec.w = 0;
    csr_rec[pos] = rec;
}

// ---------------- per-layer kernels ----------------

// Layer-1 GEMM via MFMA, K=32 (single step): Xfeat[N][32] @ Wp1 -> XL|XR.
__global__ __launch_bounds__(256) void gemm_mfma1(
    const __hip_bfloat16* __restrict__ Xf,   // [N][32]
    const __hip_bfloat16* __restrict__ Wp,   // packed frags, 8192 bf16
    const float* __restrict__ bl, const float* __restrict__ br,
    __hip_bfloat16* __restrict__ XL, __hip_bfloat16* __restrict__ XR, int N)
{
    __shared__ unsigned short sT[64 * 256];   // 32 KB output tile
    int lane = threadIdx.x & 63;
    int wave = threadIdx.x >> 6;
    int row0 = blockIdx.x * 64;
    int m_lane = lane & 15;
    int quad = lane >> 4;
    const unsigned short* Xu = (const unsigned short*)Xf;
    const unsigned short* Wu = (const unsigned short*)Wp;

    f32x4 acc[4][4];
#pragma unroll
    for (int mt = 0; mt < 4; mt++)
#pragma unroll
        for (int nt = 0; nt < 4; nt++) acc[mt][nt] = (f32x4){0.f, 0.f, 0.f, 0.f};

    bf16x8 a[4], b[4];
#pragma unroll
    for (int mt = 0; mt < 4; mt++)
        a[mt] = *(const bf16x8*)(Xu + (size_t)(row0 + mt * 16 + m_lane) * 32 + quad * 8);
#pragma unroll
    for (int nt = 0; nt < 4; nt++)
        b[nt] = *(const bf16x8*)(Wu + ((wave * 4 + nt) * 64 + lane) * 8);
#pragma unroll
    for (int mt = 0; mt < 4; mt++)
#pragma unroll
        for (int nt = 0; nt < 4; nt++)
            acc[mt][nt] = __builtin_amdgcn_mfma_f32_16x16x32_bf16(
                a[mt], b[nt], acc[mt][nt], 0, 0, 0);

#pragma unroll
    for (int nt = 0; nt < 4; nt++) {
        int col = wave * 64 + nt * 16 + m_lane;
        float bv = (col < 128) ? bl[col] : br[col - 128];
#pragma unroll
        for (int mt = 0; mt < 4; mt++) {
            int rbase = mt * 16 + quad * 4;
#pragma unroll
            for (int reg = 0; reg < 4; reg++)
                sT[(rbase + reg) * 256 + col] = f2b(acc[mt][nt][reg] + bv);
        }
    }

    __syncthreads();

    unsigned short* XLu = (unsigned short*)XL;
    unsigned short* XRu = (unsigned short*)XR;
    int t = threadIdx.x;
#pragma unroll
    for (int q = 0; q < 4; q++) {
        int s = t * 32 + q * 8;
        int r = s >> 7, c = s & 127;
        *(u16x8*)(XLu + (size_t)(row0 + r) * 128 + c) = *(const u16x8*)&sT[r * 256 + c];
        *(u16x8*)(XRu + (size_t)(row0 + r) * 128 + c) = *(const u16x8*)&sT[r * 256 + 128 + c];
    }
}

// Layers 2/3 GEMM via MFMA (K=128) with LDS-staged coalesced epilogue.
__global__ __launch_bounds__(256) void gemm_mfma(
    const __hip_bfloat16* H,               // [N][128]  (aliases XR)
    const __hip_bfloat16* __restrict__ Wp, // packed frags, 32768 bf16
    const float* __restrict__ bl, const float* __restrict__ br,
    __hip_bfloat16* __restrict__ XL, __hip_bfloat16* XR, int N)
{
    __shared__ unsigned short sT[64 * 256];   // 32 KB output tile
    int lane = threadIdx.x & 63;
    int wave = threadIdx.x >> 6;
    int row0 = blockIdx.x * 64;
    int m_lane = lane & 15;
    int quad = lane >> 4;
    const unsigned short* Hu = (const unsigned short*)H;
    const unsigned short* Wu = (const unsigned short*)Wp;

    f32x4 acc[4][4];
#pragma unroll
    for (int mt = 0; mt < 4; mt++)
#pragma unroll
        for (int nt = 0; nt < 4; nt++) acc[mt][nt] = (f32x4){0.f, 0.f, 0.f, 0.f};

#pragma unroll
    for (int ks = 0; ks < 4; ks++) {
        int koff = ks * 32 + quad * 8;
        bf16x8 a[4], b[4];
#pragma unroll
        for (int mt = 0; mt < 4; mt++)
            a[mt] = *(const bf16x8*)(Hu + (size_t)(row0 + mt * 16 + m_lane) * 128 + koff);
#pragma unroll
        for (int nt = 0; nt < 4; nt++)
            b[nt] = *(const bf16x8*)(Wu + ((((wave * 4 + nt) * 4) + ks) * 64 + lane) * 8);
#pragma unroll
        for (int mt = 0; mt < 4; mt++)
#pragma unroll
            for (int nt = 0; nt < 4; nt++)
                acc[mt][nt] = __builtin_amdgcn_mfma_f32_16x16x32_bf16(
                    a[mt], b[nt], acc[mt][nt], 0, 0, 0);
    }

#pragma unroll
    for (int nt = 0; nt < 4; nt++) {
        int col = wave * 64 + nt * 16 + m_lane;
        float bv = (col < 128) ? bl[col] : br[col - 128];
#pragma unroll
        for (int mt = 0; mt < 4; mt++) {
            int rbase = mt * 16 + quad * 4;
#pragma unroll
            for (int reg = 0; reg < 4; reg++)
                sT[(rbase + reg) * 256 + col] = f2b(acc[mt][nt][reg] + bv);
        }
    }

    __syncthreads();   // also drains all H loads before any XR store

    unsigned short* XLu = (unsigned short*)XL;
    unsigned short* XRu = (unsigned short*)XR;
    int t = threadIdx.x;
#pragma unroll
    for (int q = 0; q < 4; q++) {
        int s = t * 32 + q * 8;            // short index within 64x128 tile
        int r = s >> 7, c = s & 127;
        *(u16x8*)(XLu + (size_t)(row0 + r) * 128 + c) = *(const u16x8*)&sT[r * 256 + c];
        *(u16x8*)(XRu + (size_t)(row0 + r) * 128 + c) = *(const u16x8*)&sT[r * 256 + 128 + c];
    }
}

// FUSED logits + softmax + aggregate. 16-lane sub-waves, 4 nodes/wave.
// R27 = R26 pipeline with the per-edge column loop as 4x float2 (pk-f32).
__global__ __launch_bounds__(256) void gat_fused(
    const int4* __restrict__ meta, const int4* __restrict__ csr_rec,
    const float* __restrict__ bond_emb, const float* __restrict__ bool_emb,
    const __hip_bfloat16* __restrict__ XL, const __hip_bfloat16* XR,
    const float* __restrict__ We,        // [13][128]
    const float* __restrict__ att,       // [128]
    const float* __restrict__ bias,     // [128]
    __hip_bfloat16* OUT, int N)
{
    __shared__ float sTbt[22 * TBT_S];   // bond_emb[bt] @ We[0:8], padded stride
    __shared__ float sTca[4 * TBT_S];    // bool-pair terms
    __shared__ float sW8[128];           // We[8,:]

    for (int i = threadIdx.x; i < 22 * 128; i += 256) {
        int bt = i >> 7, c = i & 127;
        float s = 0.f;
#pragma unroll
        for (int k = 0; k < 8; k++) s = fmaf(bond_emb[bt * 8 + k], We[k * 128 + c], s);
        sTbt[bt * TBT_S + c] = s;
    }
    for (int i = threadIdx.x; i < 4 * 128; i += 256) {
        int idx = i >> 7, c = i & 127;
        int cj = idx >> 1, ar = idx & 1;
        float s = bool_emb[cj * 2]     * We[9 * 128 + c]
                + bool_emb[cj * 2 + 1] * We[10 * 128 + c]
                + bool_emb[ar * 2]     * We[11 * 128 + c]
                + bool_emb[ar * 2 + 1] * We[12 * 128 + c];
        sTca[idx * TBT_S + c] = s;
    }
    if (threadIdx.x < 128) sW8[threadIdx.x] = We[8 * 128 + threadIdx.x];
    __syncthreads();

    int lane = threadIdx.x & 63;
    int wave = threadIdx.x >> 6;
    int sl   = lane & 15;
    int sw   = lane >> 4;
    int cbase = sl * 8;

    f32x2 a82[4], bs82[4], w882[4];
    {
        float4 t0 = *(const float4*)&att[cbase],  t1 = *(const float4*)&att[cbase + 4];
        float4 u0 = *(const float4*)&bias[cbase], u1 = *(const float4*)&bias[cbase + 4];
        float4 v0 = *(const float4*)&sW8[cbase],  v1 = *(const float4*)&sW8[cbase + 4];
        a82[0] = (f32x2){t0.x, t0.y};  a82[1] = (f32x2){t0.z, t0.w};
        a82[2] = (f32x2){t1.x, t1.y};  a82[3] = (f32x2){t1.z, t1.w};
        bs82[0] = (f32x2){u0.x, u0.y}; bs82[1] = (f32x2){u0.z, u0.w};
        bs82[2] = (f32x2){u1.x, u1.y}; bs82[3] = (f32x2){u1.z, u1.w};
        w882[0] = (f32x2){v0.x, v0.y}; w882[1] = (f32x2){v0.z, v0.w};
        w882[2] = (f32x2){v1.x, v1.y}; w882[3] = (f32x2){v1.z, v1.w};
    }

    const unsigned short* XLu = (const unsigned short*)XL;
    const unsigned short* XRu = (const unsigned short*)XR;
    unsigned short* OUTu = (unsigned short*)OUT;

    int group = (blockIdx.x * 4 + wave) * 4 + sw;   // global sub-wave id
    int stride = gridDim.x * 16;

    if (group >= N) return;

    // ---- pipeline prologue ----
    int4 mt  = meta[group];                               // node i
    int ni   = group + stride;
    int4 mtn = meta[(ni < N) ? ni : (N - 1)];             // node i+1
    int4 rc[4];                                           // recs for i, chunk 0
    {
        int rp0 = mt.x, dg0 = mt.y;
#pragma unroll
        for (int jj = 0; jj < 4; jj++)
            rc[jj] = csr_rec[rp0 + (jj < dg0 ? jj : 0)];  // clamped: always valid
    }

    for (int idx = group; idx < N; idx += stride) {
        const int rp = mt.x, dg = mt.y, n = mt.z;

        // independent long-latency issues at iteration top:
        u16x8 uxr = *(const u16x8*)(XRu + (size_t)n * 128 + cbase);     // own XR
        u16x8 un  = *(const u16x8*)(XLu + (size_t)n * 128 + cbase);     // self XL
        int i2 = idx + 2 * stride;
        int4 mt2 = meta[(i2 < N) ? i2 : (N - 1)];                       // node i+2

        f32x2 xr2[4];
        b2f2(uxr, xr2);

        float runs = 0.f;
        f32x2 acc2[4], ets2[4];
#pragma unroll
        for (int i = 0; i < 4; i++) {
            acc2[i] = (f32x2){0.f, 0.f};
            ets2[i] = (f32x2){0.f, 0.f};
        }

        int j = 0;
        do {   // runs once even for dg==0 (cnt=0) so rc advances to next node
            int cnt = dg - j;
            cnt = cnt < 0 ? 0 : (cnt > 4 ? 4 : cnt);

            // uv gathers issue NOW from prefetched records (one memory round);
            // GUARDED (R24: unconditional clamped loads lengthen vmcnt drain)
            u16x8 uv[4];
#pragma unroll
            for (int jj = 0; jj < 4; jj++)
                if (jj < cnt)
                    uv[jj] = *(const u16x8*)(XLu + (size_t)rc[jj].x * 128 + cbase);

            // prefetch next chunk: in-node j+4, else next node's first chunk
            // (mtn is register-resident thanks to the 2-deep meta pipeline)
            int innode = (j + 4 < dg);
            int nb = innode ? (rp + j + 4) : mtn.x;
            int nd = innode ? (dg - j - 4) : mtn.y;
            int4 rn[4];
#pragma unroll
            for (int jj = 0; jj < 4; jj++)
                rn[jj] = csr_rec[nb + (jj < nd ? jj : 0)];   // clamped: valid

            // merged per-edge phase (R26), packed-f32 column math (R27).
#pragma unroll
            for (int jj = 0; jj < 4; jj++) {
                if (jj >= cnt) continue;
                int bt = rc[jj].y & 0xFF;
                int ca = (((rc[jj].y >> 8) & 1) << 1) | ((rc[jj].y >> 16) & 1);
                float ec = __int_as_float(rc[jj].z);
                const f32x2* tb = (const f32x2*)&sTbt[bt * TBT_S + cbase];
                const f32x2* tc = (const f32x2*)&sTca[ca * TBT_S + cbase];
                f32x2 uvf[4];
                b2f2(uv[jj], uvf);
                f32x2 ec2 = (f32x2){ec, ec};
                f32x2 ps = (f32x2){0.f, 0.f};
#pragma unroll
                for (int i = 0; i < 4; i++) {
                    f32x2 et = __builtin_elementwise_fma(ec2, w882[i], tb[i] + tc[i]);
                    ets2[i] += et;
                    f32x2 v = xr2[i] + uvf[i] + et;
                    f32x2 m = __builtin_elementwise_max(v, 0.2f * v);  // leaky 0.2
                    ps = __builtin_elementwise_fma(m, a82[i], ps);
                }
                float p = red16(ps.x + ps.y);  // DPP reduce, no DS ops
                float wgt = __expf(p);
                runs += wgt;
                f32x2 w2 = (f32x2){wgt, wgt};
#pragma unroll
                for (int i = 0; i < 4; i++)
                    acc2[i] = __builtin_elementwise_fma(w2, uvf[i], acc2[i]);
            }
#pragma unroll
            for (int jj = 0; jj < 4; jj++) rc[jj] = rn[jj];
            j += 4;
        } while (j < dg);

        {   // self loop (un in flight since iteration top)
            float invd = 1.f / (float)(dg > 0 ? dg : 1);
            f32x2 iv2 = (f32x2){invd, invd};
            f32x2 unf[4];
            b2f2(un, unf);
            f32x2 ps = (f32x2){0.f, 0.f};
#pragma unroll
            for (int i = 0; i < 4; i++) {
                f32x2 v = __builtin_elementwise_fma(ets2[i], iv2, xr2[i] + unf[i]);
                f32x2 m = __builtin_elementwise_max(v, 0.2f * v);
                ps = __builtin_elementwise_fma(m, a82[i], ps);
            }
            float p = red16(ps.x + ps.y);
            float wgt = __expf(p);
            runs += wgt;
            f32x2 w2 = (f32x2){wgt, wgt};
#pragma unroll
            for (int i = 0; i < 4; i++)
                acc2[i] = __builtin_elementwise_fma(w2, unf[i], acc2[i]);
        }

        float inv = 1.f / runs;
        f32x2 iv2 = (f32x2){inv, inv};
        u16x8 o;
#pragma unroll
        for (int i = 0; i < 4; i++) {
            f32x2 r = __builtin_elementwise_fma(acc2[i], iv2, bs82[i]);
            f32x2 z = (f32x2){0.f, 0.f};
            r = __builtin_elementwise_max(r, z);   // ReLU
            o[2 * i]     = f2b(r.x);
            o[2 * i + 1] = f2b(r.y);
        }
        *(u16x8*)(OUTu + (size_t)n * 128 + cbase) = o;

        // rotate meta pipeline
        mt = mtn; mtn = mt2;
    }
}

// Global max pool (bf16 H) into fp32 d_out (zeroed; values >= 0 -> int max ok).
// R31: original structure (proven, never in top-5): 1 col/thread (coalesced
// 256B/wave row reads), serial 64-node run, atomicMax ONLY at graph
// boundaries (~1.6M total) — the atomic-count-minimal layout.
__global__ __launch_bounds__(128) void pool_max(
    const __hip_bfloat16* __restrict__ H, const int* __restrict__ batch,
    float* __restrict__ out, int N)
{
    int c = threadIdx.x;
    int n0 = blockIdx.x * 64;
    int nend = n0 + 64; if (nend > N) nend = N;
    const unsigned short* Hu = (const unsigned short*)H;
    int g_cur = -1;
    float acc = 0.f;
    for (int n = n0; n < nend; ++n) {
        int g = batch[n];
        if (g != g_cur) {
            if (g_cur >= 0)
                atomicMax((int*)out + (size_t)g_cur * 128 + c, __float_as_int(acc));
            g_cur = g;
            acc = 0.f;
        }
        acc = fmaxf(acc, b2f(Hu[(size_t)n * 128 + c]));
    }
    if (g_cur >= 0)
        atomicMax((int*)out + (size_t)g_cur * 128 + c, __float_as_int(acc));
}

// ---------------------------------------------------------------------------

static inline size_t align_up(size_t x, size_t a) { return (x + a - 1) & ~(a - 1); }
static inline int cdiv(int a, int b) { return (a + b - 1) / b; }

extern "C" void kernel_launch(void* const* d_in, const int* in_sizes, int n_in,
                              void* d_out, int out_size, void* d_ws, size_t ws_size,
                              hipStream_t stream)
{
    const int N = in_sizes[0];          // 200000 (multiple of 64)
    const int E = in_sizes[3];          // 800000

    const int*   atom_num  = (const int*)d_in[0];
    const int*   atom_arom = (const int*)d_in[1];
    const float* x_cont    = (const float*)d_in[2];
    const int*   bond_type = (const int*)d_in[3];
    const float* edge_cont = (const float*)d_in[4];
    const int*   bond_conj = (const int*)d_in[5];
    const int*   bond_arom = (const int*)d_in[6];
    const int*   e_src     = (const int*)d_in[7];
    const int*   e_dst     = e_src + E;
    const int*   batch     = (const int*)d_in[8];
    const float* atom_emb  = (const float*)d_in[9];
    const float* bond_emb  = (const float*)d_in[10];
    const float* bool_emb  = (const float*)d_in[11];
    const float* Wl1 = (const float*)d_in[12]; const float* bl1 = (const float*)d_in[13];
    const float* Wr1 = (const float*)d_in[14]; const float* br1 = (const float*)d_in[15];
    const float* We1 = (const float*)d_in[16]; const float* att1 = (const float*)d_in[17];
    const float* bias1 = (const float*)d_in[18];
    const float* Wl2 = (const float*)d_in[19]; const float* bl2 = (const float*)d_in[20];
    const float* Wr2 = (const float*)d_in[21]; const float* br2 = (const float*)d_in[22];
    const float* We2 = (const float*)d_in[23]; const float* att2 = (const float*)d_in[24];
    const float* bias2 = (const float*)d_in[25];
    float* out = (float*)d_out;

    const int nsb = cdiv(N, SORT_BLK);  // sort blocks (196)

    // ---- workspace layout (~125 MB; ws_size is 256 MB) ----
    char* w = (char*)d_ws;
    size_t off = 0;
    auto alloc = [&](size_t bytes) {
        void* p = w + off;
        off = align_up(off + bytes, 256);
        return p;
    };
    __hip_bfloat16* A  = (__hip_bfloat16*)alloc((size_t)N * 128 * 2);   // XL
    __hip_bfloat16* B  = (__hip_bfloat16*)alloc((size_t)N * 128 * 2);   // XR / H
    __hip_bfloat16* Xf = (__hip_bfloat16*)alloc((size_t)N * 32 * 2);    // layer-1 feats
    __hip_bfloat16* Wp = (__hip_bfloat16*)alloc((size_t)32768 * 2);     // packed W2
    __hip_bfloat16* Wp1= (__hip_bfloat16*)alloc((size_t)8192 * 2);      // packed W1
    int*   degcnt  = (int*)alloc((size_t)2 * N * 4);
    int*   deg     = degcnt;
    int*   cnt     = degcnt + N;
    int4*  csr_rec = (int4*)alloc((size_t)E * 16);
    int4*  meta    = (int4*)alloc((size_t)N * 16);
    int*   nrp     = (int*)alloc((size_t)N * 4);
    int*   block_hist = (int*)alloc((size_t)nsb * 512 * 4);
    int*   bin_base   = (int*)alloc(512 * 4);
    int*   edge_base  = (int*)alloc(512 * 4);
    size_t required = off;

    fprintf(stderr, "[GNN] ws_size=%zu required=%zu%s\n", ws_size, required,
            ws_size < required ? "  INSUFFICIENT - skipping" : "");
    if (ws_size < required) return;

    // ---- consolidated init (zeros + packs + feature build), one dispatch ----
    int bz1 = cdiv(2 * N, 256);
    int bz2 = cdiv(out_size, 256);
    int bpw = 32768 / 256;
    int bpw1 = 8192 / 256;
    int bbx = cdiv(N, 256);
    int e_z1 = bz1, e_z2 = e_z1 + bz2, e_pw = e_z2 + bpw, e_pw1 = e_pw + bpw1;
    prep_init<<<e_pw1 + bbx, 256, 0, stream>>>(
        degcnt, 2 * N, (int*)out, out_size,
        Wl2, Wr2, Wp, Wl1, Wr1, Wp1,
        atom_num, atom_arom, x_cont, atom_emb, bool_emb, Xf, N,
        e_z1, e_z2, e_pw, e_pw1);

    // ---- prep: degree sort + sorted CSR (5 dispatches after prep_init) ----
    count_deg<<<cdiv(E, 256), 256, 0, stream>>>(e_dst, deg, E);
    sort_hist<<<nsb, 256, 0, stream>>>(deg, block_hist, N);
    sort_scan<<<1, 512, 0, stream>>>(block_hist, bin_base, edge_base, nsb);
    sort_scatter<<<nsb, 256, 0, stream>>>(deg, block_hist, bin_base, edge_base,
                                          meta, nrp, N);
    csr_fill<<<cdiv(E, 256), 256, 0, stream>>>(e_src, e_dst, bond_type, edge_cont,
                                               bond_conj, bond_arom, nrp, cnt,
                                               csr_rec, E);

    // R26/R27: proven geometry.
    const int fused_blocks = 1536;

    // ---- layer 1: Xf -> A(XL), B(XR) via MFMA; fused -> B(H1) ----
    gemm_mfma1<<<N / 64, 256, 0, stream>>>(Xf, Wp1, bl1, br1, A, B, N);
    gat_fused<<<fused_blocks, 256, 0, stream>>>(
        meta, csr_rec, bond_emb, bool_emb, A, B, We1, att1, bias1, B, N);

    // ---- layers 2 and 3 (shared weights): B -> A, B(in-place); fused -> B ----
    for (int layer = 0; layer < 2; ++layer) {
        gemm_mfma<<<N / 64, 256, 0, stream>>>(B, Wp, bl2, br2, A, B, N);
        gat_fused<<<fused_blocks, 256, 0, stream>>>(
            meta, csr_rec, bond_emb, bool_emb, A, B, We2, att2, bias2, B, N);
    }

    // ---- pooling directly into d_out ----
    pool_max<<<cdiv(N, 64), 128, 0, stream>>>(B, batch, out, N);
}